// Round 6
// baseline (437.423 us; speedup 1.0000x reference)
//
#include <hip/hip_runtime.h>
#include <math.h>

#define N_NODES 10000
#define N_EDGES 160000
#define G_SEG 16
#define ZDIM 10
#define KDIM 64
#define NBESS 8
#define HIDR 16
#define RMAXF 5.0f
#define AVG_NEI_F 16.0f
#define TBINS 1024

__device__ __forceinline__ float siluf(float x){ float s = 1.0f/(1.0f+expf(-x)); return x*s; }
__device__ __forceinline__ float dsiluf(float x){ float s = 1.0f/(1.0f+expf(-x)); return s*(1.0f + x*(1.0f-s)); }

__device__ __forceinline__ float waveReduce(float v){
  for (int off = 32; off > 0; off >>= 1) v += __shfl_down(v, off);
  return v;
}

__device__ __forceinline__ void tp_decode(float tp, int& b, float& fr, float& wm){
  float tpe = fmaxf(tp, 0.f);
  b = (int)tpe; if (b > TBINS-1) b = TBINS-1;
  fr = tpe - (float)b;
  wm = (tp >= 0.f) ? 1.f : 0.f;
}

// ---------------- merged setup: folded tensors + transposes + node init ----------------
__global__ __launch_bounds__(256) void k_setup(
    const float* We, const float* Wup, const float* Wsc,
    const float* Wout, const float* Wmix,
    const float* attrs, const float* aE,
    float* M0, float* Msc0,
    float* WoT0, float* WoT1, float* WmixT0, float* WmixT1,
    float* WupT1, float* WscT1,
    int* z_buf, float* e_node){
  int blk = blockIdx.x, tid = threadIdx.x;
  if (blk < 5){
    int idx = blk*256 + tid;
    if (idx < 1280){
      int which = idx >= 640;
      int t = which ? idx - 640 : idx;
      int z = t >> 6, j = t & 63;
      float acc = 0.f;
      if (!which){
        #pragma unroll 8
        for (int k = 0; k < KDIM; k++) acc += We[z*KDIM + k] * Wup[k*KDIM + j];
        M0[z*KDIM + j] = acc;
      } else {
        #pragma unroll 8
        for (int k = 0; k < KDIM; k++) acc += We[z*KDIM + k] * Wsc[(z*KDIM + k)*KDIM + j];
        Msc0[z*KDIM + j] = acc;
      }
    }
  } else if (blk < 245){
    int t = (blk-5)*256 + tid;   // 0..61439
    if (t < 20480){
      int arr = t >> 12;
      int rem = t & 4095;
      int j = rem >> 6, k = rem & 63;
      float v; float* dst;
      switch(arr){
        case 0: v = Wout[k*KDIM + j];                 dst = WoT0;   break;
        case 1: v = Wout[3*KDIM*KDIM + k*KDIM + j];   dst = WoT1;   break;
        case 2: v = Wmix[k*KDIM + j];                 dst = WmixT0; break;
        case 3: v = Wmix[KDIM*KDIM + k*KDIM + j];     dst = WmixT1; break;
        default:v = Wup[KDIM*KDIM + k*KDIM + j];      dst = WupT1;  break;
      }
      dst[rem] = v;
    } else {
      int idx2 = t - 20480;
      int z = idx2 >> 12;
      int rem = idx2 & 4095;
      int j = rem >> 6, k = rem & 63;
      WscT1[(z*KDIM + j)*KDIM + k] = Wsc[((ZDIM + z)*KDIM + k)*KDIM + j];
    }
  } else {
    int n = (blk-245)*256 + tid;
    if (n < N_NODES){
      int z = 0;
      for (int i = 1; i < ZDIM; i++) if (attrs[n*ZDIM+i] > 0.5f) z = i;
      z_buf[n] = z;
      e_node[n] = aE[z];
    }
  }
}

// edge geometry + packed edge meta + CSR degree counting
__global__ __launch_bounds__(256) void k_edge_setup(const float* pos, const float* shifts, const int* ei,
                                                    const int* z_buf,
                                                    float4* evec, int4* emeta,
                                                    int* cnt_r, int* cnt_s){
  int e = blockIdx.x*256 + threadIdx.x;
  int s = ei[e], rcv = ei[N_EDGES + e];
  float dx = pos[rcv*3+0] - pos[s*3+0] + shifts[e*3+0];
  float dy = pos[rcv*3+1] - pos[s*3+1] + shifts[e*3+1];
  float dz = pos[rcv*3+2] - pos[s*3+2] + shifts[e*3+2];
  float r = sqrtf(dx*dx + dy*dy + dz*dz + 1e-9f);
  evec[e] = make_float4(dx, dy, dz, r);
  float tp = (r < RMAXF) ? r * (TBINS / RMAXF) : -1.f;
  emeta[e] = make_int4(__float_as_int(tp), s, rcv, z_buf[s]);
  atomicAdd(&cnt_s[s], 1);
  atomicAdd(&cnt_r[rcv], 1);
}

__global__ __launch_bounds__(1024) void k_scan(const int* cnt_r, int* ptr_r, int* cur_r,
                                               const int* cnt_s, int* ptr_s, int* cur_s){
  __shared__ int part[1024];
  int tid = threadIdx.x;
  const int* cnt = blockIdx.x ? cnt_s : cnt_r;
  int* ptr = blockIdx.x ? ptr_s : ptr_r;
  int* cur = blockIdx.x ? cur_s : cur_r;
  const int per = 10;
  int start = tid*per;
  int s = 0;
  for (int t = 0; t < per; t++){ int i = start + t; if (i < N_NODES) s += cnt[i]; }
  part[tid] = s; __syncthreads();
  for (int d = 1; d < 1024; d <<= 1){
    int v = (tid >= d) ? part[tid-d] : 0;
    __syncthreads();
    part[tid] += v;
    __syncthreads();
  }
  int run = part[tid] - s;
  for (int t = 0; t < per; t++){
    int i = start + t;
    if (i < N_NODES){ ptr[i] = run; cur[i] = run; run += cnt[i]; }
  }
  if (tid == 1023) ptr[N_NODES] = part[1023];
}

__global__ __launch_bounds__(256) void k_fill(const int4* emeta, int* cur_r, int* cur_s,
                                              int4* pr_pack, int4* ps_pack){
  int e = blockIdx.x*256 + threadIdx.x;
  int4 m = emeta[e];            // {tp_bits, snd, rcv, ez}
  int p = atomicAdd(&cur_s[m.y], 1);
  ps_pack[p] = make_int4(m.x, m.z, e, 0);          // {tp, rcv, eid}
  int p2 = atomicAdd(&cur_r[m.z], 1);
  pr_pack[p2] = make_int4(m.x, m.y, m.w, e);       // {tp, snd, ez, eid}
}

// ---------------- tables ----------------
// Ft4_l[bin*32 + c] = {F[b][2c], F[b+1][2c], F[b][2c+1], F[b+1][2c+1]}   (2 channels/lane)
// dF4[(bin*64 + j)] = {d0[b], d0[b+1], d1[b], d1[b+1]}                    (per-channel, for gr2)
__global__ __launch_bounds__(64) void k_table(const float* R1g, const float* R2g,
                                              const float* R3g, const float* R4g,
                                              float* Ft4_0, float* Ft4_1, float* dF4f){
  int t = blockIdx.x, j = threadIdx.x;
  __shared__ float efs[NBESS], defs[NBESS];
  __shared__ float xs[KDIM], dxs[KDIM];
  if (j < NBESS){
    double r = (double)t * (double)RMAXF / (double)TBINS;
    double w = (double)(j+1) * M_PI / (double)RMAXF;
    double c = sqrt(2.0 / (double)RMAXF);
    double bess, dbess;
    if (r < 1e-12){ bess = c*w; dbess = 0.0; }
    else {
      double sw = sin(w*r), cw = cos(w*r);
      bess = c*sw/r;
      dbess = c*(w*cw*r - sw)/(r*r);
    }
    double xx = r / (double)RMAXF;
    double f = 0.0, df = 0.0;
    if (xx < 1.0){
      double x2 = xx*xx, x4 = x2*x2, x5 = x4*xx, x6 = x5*xx, x7 = x6*xx;
      f = 1.0 - 21.0*x5 + 35.0*x6 - 15.0*x7;
      df = (-105.0*x4 + 210.0*x5 - 105.0*x6) / (double)RMAXF;
    }
    efs[j]  = (float)(bess*f);
    defs[j] = (float)(dbess*f + bess*df);
  }
  __syncthreads();
  int c = j >> 1, comp = j & 1;
  for (int i = 0; i < 2; i++){
    const float* R1 = R1g + i*NBESS*KDIM;
    const float* R2 = R2g + i*KDIM*KDIM;
    const float* R3 = R3g + i*KDIM*KDIM;
    const float* R4 = R4g + i*KDIM*KDIM;
    float z = 0.f, dz = 0.f;
    for (int b = 0; b < NBESS; b++){ float w = R1[b*KDIM+j]; z += efs[b]*w; dz += defs[b]*w; }
    float v = siluf(z), dv = dsiluf(z)*dz;
    xs[j] = v; dxs[j] = dv; __syncthreads();
    z = 0.f; dz = 0.f;
    for (int k = 0; k < KDIM; k++){ float w = R2[k*KDIM+j]; z += xs[k]*w; dz += dxs[k]*w; }
    v = siluf(z); dv = dsiluf(z)*dz; __syncthreads();
    xs[j] = v; dxs[j] = dv; __syncthreads();
    z = 0.f; dz = 0.f;
    for (int k = 0; k < KDIM; k++){ float w = R3[k*KDIM+j]; z += xs[k]*w; dz += dxs[k]*w; }
    v = siluf(z); dv = dsiluf(z)*dz; __syncthreads();
    xs[j] = v; dxs[j] = dv; __syncthreads();
    z = 0.f; dz = 0.f;
    for (int k = 0; k < KDIM; k++){ float w = R4[k*KDIM+j]; z += xs[k]*w; dz += dxs[k]*w; }
    float* Ft = i ? Ft4_1 : Ft4_0;
    Ft[(t*32 + c)*4 + (comp ? 2 : 0)] = z;
    if (t > 0) Ft[((t-1)*32 + c)*4 + (comp ? 3 : 1)] = z;
    dF4f[(t*KDIM+j)*4 + 2*i] = dz;
    if (t > 0) dF4f[((t-1)*KDIM+j)*4 + 2*i + 1] = dz;
    __syncthreads();
  }
}

// 2-channel-per-lane gather macro body: half-wave h processes edges i+2u+h.
// ---------------- layer-0 forward (M0-table gather) + epilogue + h1/sc1 ----------------
__global__ __launch_bounds__(256) void k_layer0_fwd(
    const int* z_buf, const int* ptr_r, const int4* pr_pack,
    const float4* Ft4, const float* M0,
    const float* Wout0, const float* theta0, const float* Wmix0,
    const float* Msc0, const float* w_read0,
    const float* Wup1, const float* Wsc1,
    float* A0_out, float* h1, float* sc1, float* e_node){
  __shared__ float lds[4][KDIM];
  int tid = threadIdx.x;
  int w = tid >> 6, lane = tid & 63;
  int half = lane >> 5, c = lane & 31;
  const float2* M2 = (const float2*)M0;
  int node = blockIdx.x*4 + w;
  int z = z_buf[node];
  int beg = ptr_r[node], end = ptr_r[node+1];
  int deg = end - beg;
  float ax0=0.f, ay0=0.f, ax1=0.f, ay1=0.f, ax2=0.f, ay2=0.f, ax3=0.f, ay3=0.f;
  for (int base = 0; base < deg; base += 64){
    int m = min(64, deg - base);
    float tp_l = -1.f; int sz_l = 0;
    if (lane < m){
      int4 pk = pr_pack[beg + base + lane];   // {tp, snd, ez, eid}
      tp_l = __int_as_float(pk.x);
      sz_l = pk.z;
    }
    int i = 0;
    for (; i + 8 <= m; i += 8){
      float tpa = __shfl(tp_l, i + half),     tpb = __shfl(tp_l, i + 2 + half);
      float tpc = __shfl(tp_l, i + 4 + half), tpd = __shfl(tp_l, i + 6 + half);
      int za = __shfl(sz_l, i + half),     zb = __shfl(sz_l, i + 2 + half);
      int zc = __shfl(sz_l, i + 4 + half), zd = __shfl(sz_l, i + 6 + half);
      int ba, bb, bc, bd; float fa, fb, fc, fd, wa, wb, wc, wd;
      tp_decode(tpa, ba, fa, wa); tp_decode(tpb, bb, fb, wb);
      tp_decode(tpc, bc, fc, wc); tp_decode(tpd, bd, fd, wd);
      float4 Fa = Ft4[ba*32 + c]; float2 ha = M2[za*32 + c];
      float4 Fb = Ft4[bb*32 + c]; float2 hb = M2[zb*32 + c];
      float4 Fc = Ft4[bc*32 + c]; float2 hc = M2[zc*32 + c];
      float4 Fd = Ft4[bd*32 + c]; float2 hd = M2[zd*32 + c];
      ax0 += wa*(Fa.x + fa*(Fa.y-Fa.x))*ha.x; ay0 += wa*(Fa.z + fa*(Fa.w-Fa.z))*ha.y;
      ax1 += wb*(Fb.x + fb*(Fb.y-Fb.x))*hb.x; ay1 += wb*(Fb.z + fb*(Fb.w-Fb.z))*hb.y;
      ax2 += wc*(Fc.x + fc*(Fc.y-Fc.x))*hc.x; ay2 += wc*(Fc.z + fc*(Fc.w-Fc.z))*hc.y;
      ax3 += wd*(Fd.x + fd*(Fd.y-Fd.x))*hd.x; ay3 += wd*(Fd.z + fd*(Fd.w-Fd.z))*hd.y;
    }
    for (; i < m; i += 2){
      int idx = i + half;
      float tpa = __shfl(tp_l, idx < m ? idx : i);
      int za = __shfl(sz_l, idx < m ? idx : i);
      if (idx >= m) tpa = -1.f;
      int ba; float fa, wa;
      tp_decode(tpa, ba, fa, wa);
      float4 Fa = Ft4[ba*32 + c]; float2 ha = M2[za*32 + c];
      ax0 += wa*(Fa.x + fa*(Fa.y-Fa.x))*ha.x; ay0 += wa*(Fa.z + fa*(Fa.w-Fa.z))*ha.y;
    }
  }
  float ax = (ax0+ax1)+(ax2+ax3);
  float ay = (ay0+ay1)+(ay2+ay3);
  ax += __shfl_xor(ax, 32); ay += __shfl_xor(ay, 32);
  if (half == 0){
    float2* l2 = (float2*)lds[w];
    l2[c] = make_float2(ax*(1.0f/AVG_NEI_F), ay*(1.0f/AVG_NEI_F));
  }
  __syncthreads();
  float a0 = 0.f;
  #pragma unroll 4
  for (int k = 0; k < KDIM; k++) a0 += lds[w][k] * Wout0[k*KDIM + lane];
  A0_out[node*KDIM + lane] = a0;
  float t0 = theta0[(0*ZDIM + z)*KDIM + lane];
  float t1 = theta0[(1*ZDIM + z)*KDIM + lane];
  float t2 = theta0[(2*ZDIM + z)*KDIM + lane];
  float q = t0 + t1*a0 + t2*a0*a0;
  __syncthreads();
  lds[w][lane] = q*a0;
  __syncthreads();
  float f = 0.f;
  #pragma unroll 4
  for (int k = 0; k < KDIM; k++) f += lds[w][k] * Wmix0[k*KDIM + lane];
  f += Msc0[z*KDIM + lane];
  float p = f * w_read0[lane];
  p = waveReduce(p);
  if (lane == 0) e_node[node] += p;
  __syncthreads();
  lds[w][lane] = f;
  __syncthreads();
  float h = 0.f, s = 0.f;
  #pragma unroll 2
  for (int k = 0; k < KDIM; k++){
    float fv = lds[w][k];
    h += fv * Wup1[k*KDIM + lane];
    s += fv * Wsc1[(z*KDIM + k)*KDIM + lane];
  }
  h1[node*KDIM + lane] = h;
  sc1[node*KDIM + lane] = s;
}

// ---------------- layer-1 forward + node-local backward + energy atomic ----------------
__global__ __launch_bounds__(256) void k_layer1_fwd_bwd(
    const int* z_buf, const int* ptr_r, const int4* pr_pack,
    const float4* Ft4, const float* h1,
    const float* Wout1, const float* theta1, const float* Wmix1,
    const float* sc1, const float* Wr1, const float* Wr2,
    const float* WmixT1, const float* WoT1, const float* WscT1, const float* w_read0,
    const int* batch, const float* e_node,
    float2* gAr2, float* gF1, float* out_e){
  __shared__ float lds[4][KDIM];
  int tid = threadIdx.x;
  int w = tid >> 6, lane = tid & 63;
  int half = lane >> 5, c = lane & 31;
  const float2* h2 = (const float2*)h1;
  int node = blockIdx.x*4 + w;
  int beg = ptr_r[node], end = ptr_r[node+1];
  int deg = end - beg;
  float ax0=0.f, ay0=0.f, ax1=0.f, ay1=0.f, ax2=0.f, ay2=0.f, ax3=0.f, ay3=0.f;
  for (int base = 0; base < deg; base += 64){
    int m = min(64, deg - base);
    float tp_l = -1.f; int snd_l = 0;
    if (lane < m){
      int4 pk = pr_pack[beg + base + lane];
      tp_l = __int_as_float(pk.x);
      snd_l = pk.y;
    }
    int i = 0;
    for (; i + 8 <= m; i += 8){
      float tpa = __shfl(tp_l, i + half),     tpb = __shfl(tp_l, i + 2 + half);
      float tpc = __shfl(tp_l, i + 4 + half), tpd = __shfl(tp_l, i + 6 + half);
      int sa = __shfl(snd_l, i + half),     sb = __shfl(snd_l, i + 2 + half);
      int sc = __shfl(snd_l, i + 4 + half), sd = __shfl(snd_l, i + 6 + half);
      int ba, bb, bc, bd; float fa, fb, fc, fd, wa, wb, wc, wd;
      tp_decode(tpa, ba, fa, wa); tp_decode(tpb, bb, fb, wb);
      tp_decode(tpc, bc, fc, wc); tp_decode(tpd, bd, fd, wd);
      float4 Fa = Ft4[ba*32 + c]; float2 ha = h2[sa*32 + c];
      float4 Fb = Ft4[bb*32 + c]; float2 hb = h2[sb*32 + c];
      float4 Fc = Ft4[bc*32 + c]; float2 hc = h2[sc*32 + c];
      float4 Fd = Ft4[bd*32 + c]; float2 hd = h2[sd*32 + c];
      ax0 += wa*(Fa.x + fa*(Fa.y-Fa.x))*ha.x; ay0 += wa*(Fa.z + fa*(Fa.w-Fa.z))*ha.y;
      ax1 += wb*(Fb.x + fb*(Fb.y-Fb.x))*hb.x; ay1 += wb*(Fb.z + fb*(Fb.w-Fb.z))*hb.y;
      ax2 += wc*(Fc.x + fc*(Fc.y-Fc.x))*hc.x; ay2 += wc*(Fc.z + fc*(Fc.w-Fc.z))*hc.y;
      ax3 += wd*(Fd.x + fd*(Fd.y-Fd.x))*hd.x; ay3 += wd*(Fd.z + fd*(Fd.w-Fd.z))*hd.y;
    }
    for (; i < m; i += 2){
      int idx = i + half;
      float tpa = __shfl(tp_l, idx < m ? idx : i);
      int sa = __shfl(snd_l, idx < m ? idx : i);
      if (idx >= m) tpa = -1.f;
      int ba; float fa, wa;
      tp_decode(tpa, ba, fa, wa);
      float4 Fa = Ft4[ba*32 + c]; float2 ha = h2[sa*32 + c];
      ax0 += wa*(Fa.x + fa*(Fa.y-Fa.x))*ha.x; ay0 += wa*(Fa.z + fa*(Fa.w-Fa.z))*ha.y;
    }
  }
  float ax = (ax0+ax1)+(ax2+ax3);
  float ay = (ay0+ay1)+(ay2+ay3);
  ax += __shfl_xor(ax, 32); ay += __shfl_xor(ay, 32);
  if (half == 0){
    float2* l2 = (float2*)lds[w];
    l2[c] = make_float2(ax*(1.0f/AVG_NEI_F), ay*(1.0f/AVG_NEI_F));
  }
  __syncthreads();
  int z = z_buf[node];
  float a0 = 0.f;
  #pragma unroll 4
  for (int k = 0; k < KDIM; k++) a0 += lds[w][k] * Wout1[k*KDIM + lane];
  float t0 = theta1[(0*ZDIM + z)*KDIM + lane];
  float t1 = theta1[(1*ZDIM + z)*KDIM + lane];
  float t2 = theta1[(2*ZDIM + z)*KDIM + lane];
  float q = t0 + t1*a0 + t2*a0*a0;
  __syncthreads();
  lds[w][lane] = q*a0;
  __syncthreads();
  float f = 0.f;
  #pragma unroll 4
  for (int k = 0; k < KDIM; k++) f += lds[w][k] * Wmix1[k*KDIM + lane];
  f += sc1[node*KDIM + lane];
  __syncthreads();
  lds[w][lane] = f;
  __syncthreads();
  // readout
  int hh = lane & 15;
  int quad = lane >> 4;
  float tpart = 0.f;
  #pragma unroll
  for (int jj = 0; jj < 16; jj++)
    tpart += lds[w][quad*16 + jj] * Wr1[(quad*16 + jj)*HIDR + hh];
  tpart += __shfl_xor(tpart, 16);
  tpart += __shfl_xor(tpart, 32);
  float ne = siluf(tpart) * Wr2[hh];
  ne = waveReduce(ne);
  if (lane == 0){
    float e_tot = e_node[node] + 0.25f * ne;
    atomicAdd(&out_e[batch[node]], e_tot);
  }
  // ---- backward (node-local) ----
  float coeff = dsiluf(tpart) * Wr2[hh];
  float g = 0.f;
  #pragma unroll
  for (int h2i = 0; h2i < HIDR; h2i++){
    float cc = __shfl(coeff, h2i);
    g += cc * Wr1[lane*HIDR + h2i];
  }
  __syncthreads();
  lds[w][lane] = g;         // gF2
  __syncthreads();
  float gP = 0.f;
  #pragma unroll 4
  for (int j = 0; j < KDIM; j++) gP += lds[w][j] * WmixT1[j*KDIM + lane];
  float u = t0 + 2.f*t1*a0 + 3.f*t2*a0*a0;
  float gsc = 0.f;
  #pragma unroll 4
  for (int j = 0; j < KDIM; j++) gsc += lds[w][j] * WscT1[(z*KDIM + j)*KDIM + lane];
  gF1[node*KDIM + lane] = w_read0[lane] + gsc;
  __syncthreads();
  lds[w][lane] = gP * u;
  __syncthreads();
  float gAr = 0.f;
  #pragma unroll 4
  for (int j = 0; j < KDIM; j++) gAr += lds[w][j] * WoT1[j*KDIM + lane];
  gAr2[node*KDIM + lane].x = gAr * (1.0f/AVG_NEI_F);
}

// ---------------- bwd: sender-gather gH + layer-0 node bwd -> gAr0 ----------------
__global__ __launch_bounds__(256) void k_bwd_gH0(
    const int* z_buf, const int* ptr_s, const int4* ps_pack,
    const float4* Ft4_1, const float2* gAr2c, const float* WupT1, const float* gF1,
    const float* A00, const float* WmixT0, const float* WoT0, const float* theta0,
    float2* gAr2){
  __shared__ float ga[4][KDIM];
  __shared__ float gb[4][KDIM];
  int tid = threadIdx.x; int w = tid>>6, lane = tid&63;
  int half = lane >> 5, c = lane & 31;
  const float4* g4 = (const float4*)gAr2c;   // [node*32+c] = {g1(2c), g0(2c), g1(2c+1), g0(2c+1)}
  int node = blockIdx.x*4 + w;
  int beg = ptr_s[node], end = ptr_s[node+1];
  int deg = end - beg;
  float ax0=0.f, ay0=0.f, ax1=0.f, ay1=0.f, ax2=0.f, ay2=0.f, ax3=0.f, ay3=0.f;
  for (int base = 0; base < deg; base += 64){
    int m = min(64, deg - base);
    float tp_l = -1.f; int rcv_l = 0;
    if (lane < m){
      int4 pk = ps_pack[beg + base + lane];   // {tp, rcv, eid}
      tp_l = __int_as_float(pk.x);
      rcv_l = pk.y;
    }
    int i = 0;
    for (; i + 8 <= m; i += 8){
      float tpa = __shfl(tp_l, i + half),     tpb = __shfl(tp_l, i + 2 + half);
      float tpc = __shfl(tp_l, i + 4 + half), tpd = __shfl(tp_l, i + 6 + half);
      int ra = __shfl(rcv_l, i + half),     rb = __shfl(rcv_l, i + 2 + half);
      int rc = __shfl(rcv_l, i + 4 + half), rd = __shfl(rcv_l, i + 6 + half);
      int ba, bb, bc, bd; float fa, fb, fc, fd, wa, wb, wc, wd;
      tp_decode(tpa, ba, fa, wa); tp_decode(tpb, bb, fb, wb);
      tp_decode(tpc, bc, fc, wc); tp_decode(tpd, bd, fd, wd);
      float4 Fa = Ft4_1[ba*32 + c]; float4 ga_ = g4[ra*32 + c];
      float4 Fb = Ft4_1[bb*32 + c]; float4 gb_ = g4[rb*32 + c];
      float4 Fc = Ft4_1[bc*32 + c]; float4 gc_ = g4[rc*32 + c];
      float4 Fd = Ft4_1[bd*32 + c]; float4 gd_ = g4[rd*32 + c];
      ax0 += wa*(Fa.x + fa*(Fa.y-Fa.x))*ga_.x; ay0 += wa*(Fa.z + fa*(Fa.w-Fa.z))*ga_.z;
      ax1 += wb*(Fb.x + fb*(Fb.y-Fb.x))*gb_.x; ay1 += wb*(Fb.z + fb*(Fb.w-Fb.z))*gb_.z;
      ax2 += wc*(Fc.x + fc*(Fc.y-Fc.x))*gc_.x; ay2 += wc*(Fc.z + fc*(Fc.w-Fc.z))*gc_.z;
      ax3 += wd*(Fd.x + fd*(Fd.y-Fd.x))*gd_.x; ay3 += wd*(Fd.z + fd*(Fd.w-Fd.z))*gd_.z;
    }
    for (; i < m; i += 2){
      int idx = i + half;
      float tpa = __shfl(tp_l, idx < m ? idx : i);
      int ra = __shfl(rcv_l, idx < m ? idx : i);
      if (idx >= m) tpa = -1.f;
      int ba; float fa, wa;
      tp_decode(tpa, ba, fa, wa);
      float4 Fa = Ft4_1[ba*32 + c]; float4 ga_ = g4[ra*32 + c];
      ax0 += wa*(Fa.x + fa*(Fa.y-Fa.x))*ga_.x; ay0 += wa*(Fa.z + fa*(Fa.w-Fa.z))*ga_.z;
    }
  }
  float ax = (ax0+ax1)+(ax2+ax3);
  float ay = (ay0+ay1)+(ay2+ay3);
  ax += __shfl_xor(ax, 32); ay += __shfl_xor(ay, 32);
  if (half == 0){
    float2* l2 = (float2*)ga[w];
    l2[c] = make_float2(ax, ay);
  }
  __syncthreads();
  float gfh = 0.f;
  #pragma unroll 4
  for (int j = 0; j < KDIM; j++) gfh += ga[w][j] * WupT1[j*KDIM + lane];
  float gtot = gF1[node*KDIM + lane] + gfh;
  gb[w][lane] = gtot;
  __syncthreads();
  float gP = 0.f;
  #pragma unroll 4
  for (int j = 0; j < KDIM; j++) gP += gb[w][j] * WmixT0[j*KDIM + lane];
  int z = z_buf[node];
  float a = A00[node*KDIM + lane];
  float t0 = theta0[(0*ZDIM+z)*KDIM + lane];
  float t1 = theta0[(1*ZDIM+z)*KDIM + lane];
  float t2 = theta0[(2*ZDIM+z)*KDIM + lane];
  float u = t0 + 2.f*t1*a + 3.f*t2*a*a;
  __syncthreads();
  ga[w][lane] = gP * u;
  __syncthreads();
  float gAr = 0.f;
  #pragma unroll 4
  for (int j = 0; j < KDIM; j++) gAr += ga[w][j] * WoT0[j*KDIM + lane];
  gAr2[node*KDIM + lane].y = gAr * (1.0f/AVG_NEI_F);
}

// per-edge gr/r -> write into evec.w   (one wave per edge)
__global__ __launch_bounds__(256) void k_bwd_gr2(const int4* emeta, const float4* dF4,
                                                 const float2* gAr2, const float* h1, const float* M0,
                                                 float4* evec){
  int tid = threadIdx.x;
  int w = tid>>6, lane = tid&63;
  int e = blockIdx.x*4 + w;
  int4 m = emeta[e];              // {tp, snd, rcv, ez}
  float tp = __int_as_float(m.x);
  int b; float fr, wm;
  tp_decode(tp, b, fr, wm);
  float4 d4 = dF4[b*KDIM + lane];           // {d0.lo, d0.hi, d1.lo, d1.hi}
  float2 g  = gAr2[m.z*KDIM + lane];        // {g1, g0}
  float hv1 = h1[m.y*KDIM + lane];
  float hv0 = M0[m.w*KDIM + lane];
  float v = g.x*hv1*(d4.z + fr*(d4.w - d4.z)) + g.y*hv0*(d4.x + fr*(d4.y - d4.x));
  v = waveReduce(v) * wm;
  if (lane == 0){
    float r = evec[e].w;
    evec[e].w = v / r;
  }
}

// force: 16 lanes per node (deg ~16), 16 nodes per block
__global__ __launch_bounds__(256) void k_force(const int* ptr_r, const int4* pr_pack,
                                               const int* ptr_s, const int4* ps_pack,
                                               const float4* evec,
                                               float* out_f){
  int tid = threadIdx.x;
  int node = blockIdx.x*16 + (tid >> 4);
  int li = tid & 15;
  float fx=0.f, fy=0.f, fz=0.f;
  int beg = ptr_r[node], end = ptr_r[node+1];
  for (int idx = beg + li; idx < end; idx += 16){
    int e = pr_pack[idx].w;
    float4 ev = evec[e];
    fx -= ev.w*ev.x; fy -= ev.w*ev.y; fz -= ev.w*ev.z;
  }
  beg = ptr_s[node]; end = ptr_s[node+1];
  for (int idx = beg + li; idx < end; idx += 16){
    int e = ps_pack[idx].z;
    float4 ev = evec[e];
    fx += ev.w*ev.x; fy += ev.w*ev.y; fz += ev.w*ev.z;
  }
  #pragma unroll
  for (int off = 8; off > 0; off >>= 1){
    fx += __shfl_xor(fx, off);
    fy += __shfl_xor(fy, off);
    fz += __shfl_xor(fz, off);
  }
  if (li == 0){
    out_f[node*3+0] = fx; out_f[node*3+1] = fy; out_f[node*3+2] = fz;
  }
}

extern "C" void kernel_launch(void* const* d_in, const int* in_sizes, int n_in,
                              void* d_out, int out_size, void* d_ws, size_t ws_size,
                              hipStream_t stream){
  const float* pos    = (const float*)d_in[0];
  const float* attrs  = (const float*)d_in[1];
  const float* shifts = (const float*)d_in[2];
  const float* aE     = (const float*)d_in[3];
  const float* We     = (const float*)d_in[4];
  const float* Wup    = (const float*)d_in[5];
  const float* R1     = (const float*)d_in[6];
  const float* R2     = (const float*)d_in[7];
  const float* R3     = (const float*)d_in[8];
  const float* R4     = (const float*)d_in[9];
  const float* Wout   = (const float*)d_in[10];
  const float* Wsc    = (const float*)d_in[11];
  const float* theta  = (const float*)d_in[12];
  const float* Wmix   = (const float*)d_in[13];
  const float* w_read0= (const float*)d_in[14];
  const float* Wr1    = (const float*)d_in[15];
  const float* Wr2    = (const float*)d_in[16];
  const int*   ei     = (const int*)d_in[17];
  const int*   batch  = (const int*)d_in[18];

  char* base = (char*)d_ws;
  size_t off = 0;
  auto alloc = [&](size_t bytes)->void*{
    void* p = base + off;
    off = (off + bytes + 255) & ~(size_t)255;
    return p;
  };
  float4* evec   = (float4*)alloc(N_EDGES*sizeof(float4));
  int4*   emeta  = (int4*)alloc(N_EDGES*sizeof(int4));
  int4*   pr_pack= (int4*)alloc(N_EDGES*sizeof(int4));
  int4*   ps_pack= (int4*)alloc(N_EDGES*sizeof(int4));
  float*  e_node = (float*)alloc(N_NODES*sizeof(float));
  float*  h1     = (float*)alloc(N_NODES*KDIM*sizeof(float));
  float*  sc1    = (float*)alloc(N_NODES*KDIM*sizeof(float));
  float*  A00    = (float*)alloc(N_NODES*KDIM*sizeof(float));
  float*  gF1    = (float*)alloc(N_NODES*KDIM*sizeof(float));
  float2* gAr2   = (float2*)alloc(N_NODES*KDIM*sizeof(float2));
  float*  Ft4_0  = (float*)alloc((TBINS+1)*KDIM*2*sizeof(float));
  float*  Ft4_1  = (float*)alloc((TBINS+1)*KDIM*2*sizeof(float));
  float4* dF4    = (float4*)alloc((TBINS+1)*KDIM*sizeof(float4));
  float*  M0     = (float*)alloc(ZDIM*KDIM*sizeof(float));
  float*  Msc0   = (float*)alloc(ZDIM*KDIM*sizeof(float));
  float*  WoT0   = (float*)alloc(KDIM*KDIM*sizeof(float));
  float*  WoT1   = (float*)alloc(KDIM*KDIM*sizeof(float));
  float*  WmixT0 = (float*)alloc(KDIM*KDIM*sizeof(float));
  float*  WmixT1 = (float*)alloc(KDIM*KDIM*sizeof(float));
  float*  WupT1  = (float*)alloc(KDIM*KDIM*sizeof(float));
  float*  WscT1  = (float*)alloc(ZDIM*KDIM*KDIM*sizeof(float));
  int* z_buf = (int*)alloc(N_NODES*sizeof(int));
  int* cnt_r = (int*)alloc(N_NODES*sizeof(int));
  int* cnt_s = (int*)alloc(N_NODES*sizeof(int));
  int* ptr_r = (int*)alloc((N_NODES+1)*sizeof(int));
  int* ptr_s = (int*)alloc((N_NODES+1)*sizeof(int));
  int* cur_r = (int*)alloc(N_NODES*sizeof(int));
  int* cur_s = (int*)alloc(N_NODES*sizeof(int));

  float* out_e = (float*)d_out;
  float* out_f = out_e + G_SEG;

  hipMemsetAsync(d_out, 0, (size_t)out_size*sizeof(float), stream);
  hipMemsetAsync(cnt_r, 0, N_NODES*sizeof(int), stream);
  hipMemsetAsync(cnt_s, 0, N_NODES*sizeof(int), stream);

  const int NB4 = N_NODES/4;
  const int EB  = N_EDGES/256;
  const int EB4 = N_EDGES/4;

  const float* Wup1 = Wup + KDIM*KDIM;
  const float* Wsc1 = Wsc + ZDIM*KDIM*KDIM;
  const float* Wout1 = Wout + 3*KDIM*KDIM;
  const float* theta1 = theta + 3*ZDIM*KDIM;
  const float* Wmix1 = Wmix + KDIM*KDIM;

  k_setup<<<285,256,0,stream>>>(We, Wup, Wsc, Wout, Wmix, attrs, aE,
                                M0, Msc0, WoT0, WoT1, WmixT0, WmixT1, WupT1, WscT1,
                                z_buf, e_node);
  k_table<<<TBINS+1,64,0,stream>>>(R1, R2, R3, R4, Ft4_0, Ft4_1, (float*)dF4);
  k_edge_setup<<<EB,256,0,stream>>>(pos, shifts, ei, z_buf, evec, emeta, cnt_r, cnt_s);
  k_scan<<<2,1024,0,stream>>>(cnt_r, ptr_r, cur_r, cnt_s, ptr_s, cur_s);
  k_fill<<<EB,256,0,stream>>>(emeta, cur_r, cur_s, pr_pack, ps_pack);

  // ---- forward ----
  k_layer0_fwd<<<NB4,256,0,stream>>>(z_buf, ptr_r, pr_pack, (const float4*)Ft4_0, M0,
      Wout, theta, Wmix, Msc0, w_read0, Wup1, Wsc1,
      A00, h1, sc1, e_node);
  k_layer1_fwd_bwd<<<NB4,256,0,stream>>>(z_buf, ptr_r, pr_pack, (const float4*)Ft4_1, h1,
      Wout1, theta1, Wmix1, sc1, Wr1, Wr2,
      WmixT1, WoT1, WscT1, w_read0, batch, e_node,
      gAr2, gF1, out_e);

  // ---- backward ----
  k_bwd_gH0<<<NB4,256,0,stream>>>(z_buf, ptr_s, ps_pack, (const float4*)Ft4_1, gAr2, WupT1, gF1,
      A00, WmixT0, WoT0, theta, gAr2);
  k_bwd_gr2<<<EB4,256,0,stream>>>(emeta, dF4, gAr2, h1, M0, evec);
  k_force<<<N_NODES/16,256,0,stream>>>(ptr_r, pr_pack, ptr_s, ps_pack, evec, out_f);
}

// Round 7
// 422.275 us; speedup vs baseline: 1.0359x; 1.0359x over previous
//
#include <hip/hip_runtime.h>
#include <math.h>

#define N_NODES 10000
#define N_EDGES 160000
#define G_SEG 16
#define ZDIM 10
#define KDIM 64
#define NBESS 8
#define HIDR 16
#define RMAXF 5.0f
#define AVG_NEI_F 16.0f
#define TBINS 256

__device__ __forceinline__ float siluf(float x){ float s = 1.0f/(1.0f+expf(-x)); return x*s; }
__device__ __forceinline__ float dsiluf(float x){ float s = 1.0f/(1.0f+expf(-x)); return s*(1.0f + x*(1.0f-s)); }

__device__ __forceinline__ float waveReduce(float v){
  for (int off = 32; off > 0; off >>= 1) v += __shfl_down(v, off);
  return v;
}

// decode from r (CSR slots hold r; padding holds -1)
__device__ __forceinline__ void r_decode(float r, int& b, float& fr, float& wm){
  wm = (r >= 0.f) ? 1.f : 0.f;
  float tp = fmaxf(r, 0.f) * (TBINS / RMAXF);
  b = (int)tp; if (b > TBINS-1) b = TBINS-1;
  fr = tp - (float)b;
}

// ---------------- merged setup ----------------
// blocks 0-4: M0/Msc0 dots | 5-68: transposes | 69-72: P1 | 73-112: Q | 113-152: node init
__global__ __launch_bounds__(256) void k_setup(
    const float* We, const float* Wup, const float* Wsc,
    const float* Wout, const float* Wmix,
    const float* Wr1,
    const float* attrs, const float* aE,
    float* M0, float* Msc0,
    float* WoT0, float* WoT1, float* WmixT0, float* WupT1,
    float* P1, float* Qtab,
    int* z_buf, float* e_node){
  int blk = blockIdx.x, tid = threadIdx.x;
  const float* Wmix1 = Wmix + KDIM*KDIM;
  const float* Wsc1  = Wsc + ZDIM*KDIM*KDIM;
  if (blk < 5){
    int idx = blk*256 + tid;
    if (idx < 1280){
      int which = idx >= 640;
      int t = which ? idx - 640 : idx;
      int z = t >> 6, j = t & 63;
      float acc = 0.f;
      if (!which){
        #pragma unroll 8
        for (int k = 0; k < KDIM; k++) acc += We[z*KDIM + k] * Wup[k*KDIM + j];
        M0[z*KDIM + j] = acc;
      } else {
        #pragma unroll 8
        for (int k = 0; k < KDIM; k++) acc += We[z*KDIM + k] * Wsc[(z*KDIM + k)*KDIM + j];
        Msc0[z*KDIM + j] = acc;
      }
    }
  } else if (blk < 69){
    int t = (blk-5)*256 + tid;   // 0..16383
    int arr = t >> 12;
    int rem = t & 4095;
    int j = rem >> 6, k = rem & 63;
    float v; float* dst;
    switch(arr){
      case 0: v = Wout[k*KDIM + j];                 dst = WoT0;   break;
      case 1: v = Wout[3*KDIM*KDIM + k*KDIM + j];   dst = WoT1;   break;
      case 2: v = Wmix[k*KDIM + j];                 dst = WmixT0; break;
      default:v = Wup[KDIM*KDIM + k*KDIM + j];      dst = WupT1;  break;
    }
    dst[rem] = v;
  } else if (blk < 73){
    int t = (blk-69)*256 + tid;  // 0..1023
    int h = t >> 6, k = t & 63;
    float acc = 0.f;
    #pragma unroll 8
    for (int j = 0; j < KDIM; j++) acc += Wr1[j*HIDR + h] * Wmix1[k*KDIM + j];
    P1[h*KDIM + k] = acc;
  } else if (blk < 113){
    int t = (blk-73)*256 + tid;  // 0..10239
    int z = t >> 10;             // t / 1024
    int rem = t & 1023;
    int h = rem >> 6, k = rem & 63;
    float acc = 0.f;
    #pragma unroll 8
    for (int j = 0; j < KDIM; j++) acc += Wr1[j*HIDR + h] * Wsc1[(z*KDIM + k)*KDIM + j];
    Qtab[(z*HIDR + h)*KDIM + k] = acc;
  } else {
    int n = (blk-113)*256 + tid;
    if (n < N_NODES){
      int z = 0;
      for (int i = 1; i < ZDIM; i++) if (attrs[n*ZDIM+i] > 0.5f) z = i;
      z_buf[n] = z;
      e_node[n] = aE[z];
    }
  }
}

// edge geometry + packed edge meta + CSR degree counting (live edges only)
__global__ __launch_bounds__(256) void k_edge_setup(const float* pos, const float* shifts, const int* ei,
                                                    const int* z_buf,
                                                    float4* evec, int4* emeta,
                                                    int* cnt_r, int* cnt_s){
  int e = blockIdx.x*256 + threadIdx.x;
  int s = ei[e], rcv = ei[N_EDGES + e];
  float dx = pos[rcv*3+0] - pos[s*3+0] + shifts[e*3+0];
  float dy = pos[rcv*3+1] - pos[s*3+1] + shifts[e*3+1];
  float dz = pos[rcv*3+2] - pos[s*3+2] + shifts[e*3+2];
  float r = sqrtf(dx*dx + dy*dy + dz*dz + 1e-9f);
  evec[e] = make_float4(dx, dy, dz, r);
  emeta[e] = make_int4(__float_as_int(r), s, rcv, z_buf[s]);
  if (r < RMAXF){
    atomicAdd(&cnt_s[s], 1);
    atomicAdd(&cnt_r[rcv], 1);
  }
}

__global__ __launch_bounds__(1024) void k_scan(const int* cnt_r, int* ptr_r, int* cur_r,
                                               const int* cnt_s, int* ptr_s, int* cur_s){
  __shared__ int part[1024];
  int tid = threadIdx.x;
  const int* cnt = blockIdx.x ? cnt_s : cnt_r;
  int* ptr = blockIdx.x ? ptr_s : ptr_r;
  int* cur = blockIdx.x ? cur_s : cur_r;
  const int per = 10;
  int start = tid*per;
  int s = 0;
  for (int t = 0; t < per; t++){ int i = start + t; if (i < N_NODES) s += cnt[i]; }
  part[tid] = s; __syncthreads();
  for (int d = 1; d < 1024; d <<= 1){
    int v = (tid >= d) ? part[tid-d] : 0;
    __syncthreads();
    part[tid] += v;
    __syncthreads();
  }
  int run = part[tid] - s;
  for (int t = 0; t < per; t++){
    int i = start + t;
    if (i < N_NODES){ ptr[i] = run; cur[i] = run; run += cnt[i]; }
  }
  if (tid == 1023) ptr[N_NODES] = part[1023];
}

__global__ __launch_bounds__(256) void k_fill(const int4* emeta, int* cur_r, int* cur_s,
                                              int4* pr_pack, int4* ps_pack){
  int e = blockIdx.x*256 + threadIdx.x;
  int4 m = emeta[e];            // {r_bits, snd, rcv, ez}
  float r = __int_as_float(m.x);
  if (r >= RMAXF) return;
  int p = atomicAdd(&cur_s[m.y], 1);
  ps_pack[p] = make_int4(m.x, m.z, e, 0);          // {r, rcv, eid}
  int p2 = atomicAdd(&cur_r[m.z], 1);
  pr_pack[p2] = make_int4(m.x, m.y, m.w, e);       // {r, snd, ez, eid}
}

// ---------------- radial-MLP tables, float2 (F[b],F[b+1]) per layer; dF4 packed ----------------
__global__ __launch_bounds__(64) void k_table(const float* R1g, const float* R2g,
                                              const float* R3g, const float* R4g,
                                              float2* Ft2_0, float2* Ft2_1, float* dF4f){
  int t = blockIdx.x, j = threadIdx.x;
  __shared__ float efs[NBESS], defs[NBESS];
  __shared__ float xs[KDIM], dxs[KDIM];
  if (j < NBESS){
    double r = (double)t * (double)RMAXF / (double)TBINS;
    double w = (double)(j+1) * M_PI / (double)RMAXF;
    double c = sqrt(2.0 / (double)RMAXF);
    double bess, dbess;
    if (r < 1e-12){ bess = c*w; dbess = 0.0; }
    else {
      double sw = sin(w*r), cw = cos(w*r);
      bess = c*sw/r;
      dbess = c*(w*cw*r - sw)/(r*r);
    }
    double xx = r / (double)RMAXF;
    double f = 0.0, df = 0.0;
    if (xx < 1.0){
      double x2 = xx*xx, x4 = x2*x2, x5 = x4*xx, x6 = x5*xx, x7 = x6*xx;
      f = 1.0 - 21.0*x5 + 35.0*x6 - 15.0*x7;
      df = (-105.0*x4 + 210.0*x5 - 105.0*x6) / (double)RMAXF;
    }
    efs[j]  = (float)(bess*f);
    defs[j] = (float)(dbess*f + bess*df);
  }
  __syncthreads();
  for (int i = 0; i < 2; i++){
    const float* R1 = R1g + i*NBESS*KDIM;
    const float* R2 = R2g + i*KDIM*KDIM;
    const float* R3 = R3g + i*KDIM*KDIM;
    const float* R4 = R4g + i*KDIM*KDIM;
    float z = 0.f, dz = 0.f;
    for (int b = 0; b < NBESS; b++){ float w = R1[b*KDIM+j]; z += efs[b]*w; dz += defs[b]*w; }
    float v = siluf(z), dv = dsiluf(z)*dz;
    xs[j] = v; dxs[j] = dv; __syncthreads();
    z = 0.f; dz = 0.f;
    for (int k = 0; k < KDIM; k++){ float w = R2[k*KDIM+j]; z += xs[k]*w; dz += dxs[k]*w; }
    v = siluf(z); dv = dsiluf(z)*dz; __syncthreads();
    xs[j] = v; dxs[j] = dv; __syncthreads();
    z = 0.f; dz = 0.f;
    for (int k = 0; k < KDIM; k++){ float w = R3[k*KDIM+j]; z += xs[k]*w; dz += dxs[k]*w; }
    v = siluf(z); dv = dsiluf(z)*dz; __syncthreads();
    xs[j] = v; dxs[j] = dv; __syncthreads();
    z = 0.f; dz = 0.f;
    for (int k = 0; k < KDIM; k++){ float w = R4[k*KDIM+j]; z += xs[k]*w; dz += dxs[k]*w; }
    float2* Ft  = i ? Ft2_1 : Ft2_0;
    Ft[t*KDIM+j].x = z;  if (t > 0) Ft[(t-1)*KDIM+j].y = z;
    dF4f[(t*KDIM+j)*4 + 2*i] = dz;
    if (t > 0) dF4f[((t-1)*KDIM+j)*4 + 2*i + 1] = dz;
    __syncthreads();
  }
}

// ---------------- layer-0 forward (M0-table gather) + epilogue + h1/sc1 ----------------
__global__ __launch_bounds__(256) void k_layer0_fwd(
    const int* z_buf, const int* ptr_r, const int4* pr_pack,
    const float2* Ft2, const float* M0,
    const float* Wout0, const float* theta0, const float* Wmix0,
    const float* Msc0, const float* w_read0,
    const float* Wup1, const float* Wsc1,
    float* A0_out, float* h1, float* sc1, float* e_node){
  __shared__ float lds[4][KDIM];
  int tid = threadIdx.x;
  int w = tid >> 6, lane = tid & 63;
  int node = blockIdx.x*4 + w;
  int z = z_buf[node];
  int beg = ptr_r[node], end = ptr_r[node+1];
  int deg = end - beg;
  float acc0 = 0.f, acc1 = 0.f, acc2 = 0.f, acc3 = 0.f;
  for (int base = 0; base < deg; base += 64){
    int m = min(64, deg - base);
    float r_l = -1.f; int sz_l = 0;
    if (lane < m){
      int4 pk = pr_pack[beg + base + lane];   // {r, snd, ez, eid}
      r_l = __int_as_float(pk.x);
      sz_l = pk.z;
    }
    int i = 0;
    for (; i + 4 <= m; i += 4){
      float ra_ = __shfl(r_l, i),   rb_ = __shfl(r_l, i+1);
      float rc_ = __shfl(r_l, i+2), rd_ = __shfl(r_l, i+3);
      int za = __shfl(sz_l, i),   zb = __shfl(sz_l, i+1);
      int zc = __shfl(sz_l, i+2), zd = __shfl(sz_l, i+3);
      int ba, bb, bc, bd; float fa, fb, fc, fd, wa, wb, wc, wd;
      r_decode(ra_, ba, fa, wa); r_decode(rb_, bb, fb, wb);
      r_decode(rc_, bc, fc, wc); r_decode(rd_, bd, fd, wd);
      float2 Fa = Ft2[ba*KDIM + lane]; float ha = M0[za*KDIM + lane];
      float2 Fb = Ft2[bb*KDIM + lane]; float hb = M0[zb*KDIM + lane];
      float2 Fc = Ft2[bc*KDIM + lane]; float hc = M0[zc*KDIM + lane];
      float2 Fd = Ft2[bd*KDIM + lane]; float hd = M0[zd*KDIM + lane];
      acc0 += wa * (Fa.x + fa*(Fa.y - Fa.x)) * ha;
      acc1 += wb * (Fb.x + fb*(Fb.y - Fb.x)) * hb;
      acc2 += wc * (Fc.x + fc*(Fc.y - Fc.x)) * hc;
      acc3 += wd * (Fd.x + fd*(Fd.y - Fd.x)) * hd;
    }
    for (; i < m; i++){
      float ra_ = __shfl(r_l, i);
      int za = __shfl(sz_l, i);
      int ba; float fa, wa;
      r_decode(ra_, ba, fa, wa);
      float2 Fa = Ft2[ba*KDIM + lane]; float ha = M0[za*KDIM + lane];
      acc0 += wa * (Fa.x + fa*(Fa.y - Fa.x)) * ha;
    }
  }
  float acc = ((acc0 + acc1) + (acc2 + acc3)) * (1.0f/AVG_NEI_F);
  lds[w][lane] = acc;
  __syncthreads();
  float a0 = 0.f;
  #pragma unroll 4
  for (int k = 0; k < KDIM; k++) a0 += lds[w][k] * Wout0[k*KDIM + lane];
  A0_out[node*KDIM + lane] = a0;
  float t0 = theta0[(0*ZDIM + z)*KDIM + lane];
  float t1 = theta0[(1*ZDIM + z)*KDIM + lane];
  float t2 = theta0[(2*ZDIM + z)*KDIM + lane];
  float q = t0 + t1*a0 + t2*a0*a0;
  __syncthreads();
  lds[w][lane] = q*a0;
  __syncthreads();
  float f = 0.f;
  #pragma unroll 4
  for (int k = 0; k < KDIM; k++) f += lds[w][k] * Wmix0[k*KDIM + lane];
  f += Msc0[z*KDIM + lane];
  float p = f * w_read0[lane];
  p = waveReduce(p);
  if (lane == 0) e_node[node] += p;
  __syncthreads();
  lds[w][lane] = f;
  __syncthreads();
  float h = 0.f, s = 0.f;
  #pragma unroll 2
  for (int k = 0; k < KDIM; k++){
    float fv = lds[w][k];
    h += fv * Wup1[k*KDIM + lane];
    s += fv * Wsc1[(z*KDIM + k)*KDIM + lane];
  }
  h1[node*KDIM + lane] = h;
  sc1[node*KDIM + lane] = s;
}

// ---------------- layer-1 forward + node-local backward (P1/Q shortcut) + energy atomic ----------------
__global__ __launch_bounds__(256) void k_layer1_fwd_bwd(
    const int* z_buf, const int* ptr_r, const int4* pr_pack,
    const float2* Ft2, const float* h1,
    const float* Wout1, const float* theta1, const float* Wmix1,
    const float* sc1, const float* Wr1, const float* Wr2,
    const float* P1, const float* Qtab, const float* WoT1, const float* w_read0,
    const int* batch, const float* e_node,
    float2* gAr2, float* gF1, float* out_e){
  __shared__ float lds[4][KDIM];
  int tid = threadIdx.x;
  int w = tid >> 6, lane = tid & 63;
  int node = blockIdx.x*4 + w;
  int beg = ptr_r[node], end = ptr_r[node+1];
  int deg = end - beg;
  float acc0 = 0.f, acc1 = 0.f, acc2 = 0.f, acc3 = 0.f;
  for (int base = 0; base < deg; base += 64){
    int m = min(64, deg - base);
    float r_l = -1.f; int snd_l = 0;
    if (lane < m){
      int4 pk = pr_pack[beg + base + lane];
      r_l = __int_as_float(pk.x);
      snd_l = pk.y;
    }
    int i = 0;
    for (; i + 4 <= m; i += 4){
      float ra_ = __shfl(r_l, i),   rb_ = __shfl(r_l, i+1);
      float rc_ = __shfl(r_l, i+2), rd_ = __shfl(r_l, i+3);
      int sa = __shfl(snd_l, i),   sb = __shfl(snd_l, i+1);
      int sc = __shfl(snd_l, i+2), sd = __shfl(snd_l, i+3);
      int ba, bb, bc, bd; float fa, fb, fc, fd, wa, wb, wc, wd;
      r_decode(ra_, ba, fa, wa); r_decode(rb_, bb, fb, wb);
      r_decode(rc_, bc, fc, wc); r_decode(rd_, bd, fd, wd);
      float2 Fa = Ft2[ba*KDIM + lane]; float ha = h1[sa*KDIM + lane];
      float2 Fb = Ft2[bb*KDIM + lane]; float hb = h1[sb*KDIM + lane];
      float2 Fc = Ft2[bc*KDIM + lane]; float hc = h1[sc*KDIM + lane];
      float2 Fd = Ft2[bd*KDIM + lane]; float hd = h1[sd*KDIM + lane];
      acc0 += wa * (Fa.x + fa*(Fa.y - Fa.x)) * ha;
      acc1 += wb * (Fb.x + fb*(Fb.y - Fb.x)) * hb;
      acc2 += wc * (Fc.x + fc*(Fc.y - Fc.x)) * hc;
      acc3 += wd * (Fd.x + fd*(Fd.y - Fd.x)) * hd;
    }
    for (; i < m; i++){
      float ra_ = __shfl(r_l, i);
      int sa = __shfl(snd_l, i);
      int ba; float fa, wa;
      r_decode(ra_, ba, fa, wa);
      float2 Fa = Ft2[ba*KDIM + lane]; float ha = h1[sa*KDIM + lane];
      acc0 += wa * (Fa.x + fa*(Fa.y - Fa.x)) * ha;
    }
  }
  float acc = ((acc0 + acc1) + (acc2 + acc3)) * (1.0f/AVG_NEI_F);
  int z = z_buf[node];
  lds[w][lane] = acc;
  __syncthreads();
  float a0 = 0.f;
  #pragma unroll 4
  for (int k = 0; k < KDIM; k++) a0 += lds[w][k] * Wout1[k*KDIM + lane];
  float t0 = theta1[(0*ZDIM + z)*KDIM + lane];
  float t1 = theta1[(1*ZDIM + z)*KDIM + lane];
  float t2 = theta1[(2*ZDIM + z)*KDIM + lane];
  float q = t0 + t1*a0 + t2*a0*a0;
  __syncthreads();
  lds[w][lane] = q*a0;
  __syncthreads();
  float f = 0.f;
  #pragma unroll 4
  for (int k = 0; k < KDIM; k++) f += lds[w][k] * Wmix1[k*KDIM + lane];
  f += sc1[node*KDIM + lane];
  __syncthreads();
  lds[w][lane] = f;
  __syncthreads();
  // readout: t = feats2 @ Wr1 (16 hidden)
  int hh = lane & 15;
  int quad = lane >> 4;
  float tpart = 0.f;
  #pragma unroll
  for (int jj = 0; jj < 16; jj++)
    tpart += lds[w][quad*16 + jj] * Wr1[(quad*16 + jj)*HIDR + hh];
  tpart += __shfl_xor(tpart, 16);
  tpart += __shfl_xor(tpart, 32);
  float ne = siluf(tpart) * Wr2[hh];
  ne = waveReduce(ne);
  if (lane == 0){
    atomicAdd(&out_e[batch[node]], e_node[node] + 0.25f * ne);
  }
  // ---- backward (node-local), low-rank shortcut through readout ----
  float coeff = dsiluf(tpart) * Wr2[hh];   // replicated x4 across wave
  float gP = 0.f, gsc = 0.f;
  const float* Qz = Qtab + z*HIDR*KDIM;
  #pragma unroll
  for (int h2 = 0; h2 < HIDR; h2++){
    float cc = __shfl(coeff, h2);
    gP  += cc * P1[h2*KDIM + lane];
    gsc += cc * Qz[h2*KDIM + lane];
  }
  gF1[node*KDIM + lane] = w_read0[lane] + gsc;
  float u = t0 + 2.f*t1*a0 + 3.f*t2*a0*a0;
  __syncthreads();
  lds[w][lane] = gP * u;
  __syncthreads();
  float gAr = 0.f;
  #pragma unroll 4
  for (int j = 0; j < KDIM; j++) gAr += lds[w][j] * WoT1[j*KDIM + lane];
  gAr2[node*KDIM + lane].x = gAr * (1.0f/AVG_NEI_F);
}

// ---------------- bwd: sender-gather gH + layer-0 node bwd -> gAr0 ----------------
__global__ __launch_bounds__(256) void k_bwd_gH0(
    const int* z_buf, const int* ptr_s, const int4* ps_pack,
    const float2* Ft2_1, const float2* gAr2c, const float* WupT1, const float* gF1,
    const float* A00, const float* WmixT0, const float* WoT0, const float* theta0,
    float2* gAr2){
  __shared__ float ga[4][KDIM];
  __shared__ float gb[4][KDIM];
  int tid = threadIdx.x; int w = tid>>6, lane = tid&63;
  int node = blockIdx.x*4 + w;
  int beg = ptr_s[node], end = ptr_s[node+1];
  int deg = end - beg;
  float acc0 = 0.f, acc1 = 0.f, acc2 = 0.f, acc3 = 0.f;
  for (int base = 0; base < deg; base += 64){
    int m = min(64, deg - base);
    float r_l = -1.f; int rcv_l = 0;
    if (lane < m){
      int4 pk = ps_pack[beg + base + lane];   // {r, rcv, eid}
      r_l = __int_as_float(pk.x);
      rcv_l = pk.y;
    }
    int i = 0;
    for (; i + 4 <= m; i += 4){
      float ra_ = __shfl(r_l, i),   rb_ = __shfl(r_l, i+1);
      float rc_ = __shfl(r_l, i+2), rd_ = __shfl(r_l, i+3);
      int ra = __shfl(rcv_l, i),   rb = __shfl(rcv_l, i+1);
      int rc = __shfl(rcv_l, i+2), rd = __shfl(rcv_l, i+3);
      int ba, bb, bc, bd; float fa, fb, fc, fd, wa, wb, wc, wd;
      r_decode(ra_, ba, fa, wa); r_decode(rb_, bb, fb, wb);
      r_decode(rc_, bc, fc, wc); r_decode(rd_, bd, fd, wd);
      float2 Fa = Ft2_1[ba*KDIM + lane]; float ga_ = gAr2c[ra*KDIM + lane].x;
      float2 Fb = Ft2_1[bb*KDIM + lane]; float gb_ = gAr2c[rb*KDIM + lane].x;
      float2 Fc = Ft2_1[bc*KDIM + lane]; float gc_ = gAr2c[rc*KDIM + lane].x;
      float2 Fd = Ft2_1[bd*KDIM + lane]; float gd_ = gAr2c[rd*KDIM + lane].x;
      acc0 += wa * (Fa.x + fa*(Fa.y - Fa.x)) * ga_;
      acc1 += wb * (Fb.x + fb*(Fb.y - Fb.x)) * gb_;
      acc2 += wc * (Fc.x + fc*(Fc.y - Fc.x)) * gc_;
      acc3 += wd * (Fd.x + fd*(Fd.y - Fd.x)) * gd_;
    }
    for (; i < m; i++){
      float ra_ = __shfl(r_l, i);
      int ra = __shfl(rcv_l, i);
      int ba; float fa, wa;
      r_decode(ra_, ba, fa, wa);
      float2 Fa = Ft2_1[ba*KDIM + lane]; float ga_ = gAr2c[ra*KDIM + lane].x;
      acc0 += wa * (Fa.x + fa*(Fa.y - Fa.x)) * ga_;
    }
  }
  ga[w][lane] = ((acc0 + acc1) + (acc2 + acc3));
  __syncthreads();
  float gfh = 0.f;
  #pragma unroll 4
  for (int j = 0; j < KDIM; j++) gfh += ga[w][j] * WupT1[j*KDIM + lane];
  float gtot = gF1[node*KDIM + lane] + gfh;
  gb[w][lane] = gtot;
  __syncthreads();
  float gP = 0.f;
  #pragma unroll 4
  for (int j = 0; j < KDIM; j++) gP += gb[w][j] * WmixT0[j*KDIM + lane];
  int z = z_buf[node];
  float a = A00[node*KDIM + lane];
  float t0 = theta0[(0*ZDIM+z)*KDIM + lane];
  float t1 = theta0[(1*ZDIM+z)*KDIM + lane];
  float t2 = theta0[(2*ZDIM+z)*KDIM + lane];
  float u = t0 + 2.f*t1*a + 3.f*t2*a*a;
  __syncthreads();
  ga[w][lane] = gP * u;
  __syncthreads();
  float gAr = 0.f;
  #pragma unroll 4
  for (int j = 0; j < KDIM; j++) gAr += ga[w][j] * WoT0[j*KDIM + lane];
  gAr2[node*KDIM + lane].y = gAr * (1.0f/AVG_NEI_F);
}

// per-edge gr + fused force atomics (one wave per edge; dead edges exit early)
__global__ __launch_bounds__(256) void k_gr_force(const int4* emeta, const float4* evec,
                                                  const float4* dF4,
                                                  const float2* gAr2, const float* h1, const float* M0,
                                                  float* out_f){
  int tid = threadIdx.x;
  int w = tid>>6, lane = tid&63;
  int e = blockIdx.x*4 + w;
  int4 m = emeta[e];              // {r, snd, rcv, ez}
  float r = __int_as_float(m.x);
  if (r >= RMAXF) return;
  float tp = r * (TBINS / RMAXF);
  int b = (int)tp; if (b > TBINS-1) b = TBINS-1;
  float fr = tp - (float)b;
  float4 d4 = dF4[b*KDIM + lane];           // {d0.lo, d0.hi, d1.lo, d1.hi}
  float2 g  = gAr2[m.z*KDIM + lane];        // {g1, g0}
  float hv1 = h1[m.y*KDIM + lane];
  float hv0 = M0[m.w*KDIM + lane];
  float v = g.x*hv1*(d4.z + fr*(d4.w - d4.z)) + g.y*hv0*(d4.x + fr*(d4.y - d4.x));
  v = waveReduce(v);
  float s = __shfl(v, 0) / r;
  if (lane < 6){
    float4 ev = evec[e];
    int comp = lane < 3 ? lane : lane - 3;
    float cv = (comp == 0) ? ev.x : (comp == 1) ? ev.y : ev.z;
    float val = (lane < 3 ? s : -s) * cv;
    int nd = (lane < 3) ? m.y : m.z;
    atomicAdd(&out_f[nd*3 + comp], val);
  }
}

extern "C" void kernel_launch(void* const* d_in, const int* in_sizes, int n_in,
                              void* d_out, int out_size, void* d_ws, size_t ws_size,
                              hipStream_t stream){
  const float* pos    = (const float*)d_in[0];
  const float* attrs  = (const float*)d_in[1];
  const float* shifts = (const float*)d_in[2];
  const float* aE     = (const float*)d_in[3];
  const float* We     = (const float*)d_in[4];
  const float* Wup    = (const float*)d_in[5];
  const float* R1     = (const float*)d_in[6];
  const float* R2     = (const float*)d_in[7];
  const float* R3     = (const float*)d_in[8];
  const float* R4     = (const float*)d_in[9];
  const float* Wout   = (const float*)d_in[10];
  const float* Wsc    = (const float*)d_in[11];
  const float* theta  = (const float*)d_in[12];
  const float* Wmix   = (const float*)d_in[13];
  const float* w_read0= (const float*)d_in[14];
  const float* Wr1    = (const float*)d_in[15];
  const float* Wr2    = (const float*)d_in[16];
  const int*   ei     = (const int*)d_in[17];
  const int*   batch  = (const int*)d_in[18];

  char* base = (char*)d_ws;
  size_t off = 0;
  auto alloc = [&](size_t bytes)->void*{
    void* p = base + off;
    off = (off + bytes + 255) & ~(size_t)255;
    return p;
  };
  float4* evec   = (float4*)alloc(N_EDGES*sizeof(float4));
  int4*   emeta  = (int4*)alloc(N_EDGES*sizeof(int4));
  int4*   pr_pack= (int4*)alloc(N_EDGES*sizeof(int4));
  int4*   ps_pack= (int4*)alloc(N_EDGES*sizeof(int4));
  float*  e_node = (float*)alloc(N_NODES*sizeof(float));
  float*  h1     = (float*)alloc(N_NODES*KDIM*sizeof(float));
  float*  sc1    = (float*)alloc(N_NODES*KDIM*sizeof(float));
  float*  A00    = (float*)alloc(N_NODES*KDIM*sizeof(float));
  float*  gF1    = (float*)alloc(N_NODES*KDIM*sizeof(float));
  float2* gAr2   = (float2*)alloc(N_NODES*KDIM*sizeof(float2));
  float2* Ft2_0  = (float2*)alloc((TBINS+1)*KDIM*sizeof(float2));
  float2* Ft2_1  = (float2*)alloc((TBINS+1)*KDIM*sizeof(float2));
  float4* dF4    = (float4*)alloc((TBINS+1)*KDIM*sizeof(float4));
  float*  M0     = (float*)alloc(ZDIM*KDIM*sizeof(float));
  float*  Msc0   = (float*)alloc(ZDIM*KDIM*sizeof(float));
  float*  WoT0   = (float*)alloc(KDIM*KDIM*sizeof(float));
  float*  WoT1   = (float*)alloc(KDIM*KDIM*sizeof(float));
  float*  WmixT0 = (float*)alloc(KDIM*KDIM*sizeof(float));
  float*  WupT1  = (float*)alloc(KDIM*KDIM*sizeof(float));
  float*  P1     = (float*)alloc(HIDR*KDIM*sizeof(float));
  float*  Qtab   = (float*)alloc(ZDIM*HIDR*KDIM*sizeof(float));
  int* z_buf = (int*)alloc(N_NODES*sizeof(int));
  int* cnt_r = (int*)alloc(N_NODES*sizeof(int));
  int* cnt_s = (int*)alloc(N_NODES*sizeof(int));
  int* ptr_r = (int*)alloc((N_NODES+1)*sizeof(int));
  int* ptr_s = (int*)alloc((N_NODES+1)*sizeof(int));
  int* cur_r = (int*)alloc(N_NODES*sizeof(int));
  int* cur_s = (int*)alloc(N_NODES*sizeof(int));

  float* out_e = (float*)d_out;
  float* out_f = out_e + G_SEG;

  hipMemsetAsync(d_out, 0, (size_t)out_size*sizeof(float), stream);
  hipMemsetAsync(cnt_r, 0, N_NODES*sizeof(int), stream);
  hipMemsetAsync(cnt_s, 0, N_NODES*sizeof(int), stream);

  const int NB4 = N_NODES/4;
  const int EB  = N_EDGES/256;
  const int EB4 = N_EDGES/4;

  const float* Wup1 = Wup + KDIM*KDIM;
  const float* Wsc1 = Wsc + ZDIM*KDIM*KDIM;
  const float* Wout1 = Wout + 3*KDIM*KDIM;
  const float* theta1 = theta + 3*ZDIM*KDIM;
  const float* Wmix1 = Wmix + KDIM*KDIM;

  k_setup<<<153,256,0,stream>>>(We, Wup, Wsc, Wout, Wmix, Wr1, attrs, aE,
                                M0, Msc0, WoT0, WoT1, WmixT0, WupT1, P1, Qtab,
                                z_buf, e_node);
  k_table<<<TBINS+1,64,0,stream>>>(R1, R2, R3, R4, Ft2_0, Ft2_1, (float*)dF4);
  k_edge_setup<<<EB,256,0,stream>>>(pos, shifts, ei, z_buf, evec, emeta, cnt_r, cnt_s);
  k_scan<<<2,1024,0,stream>>>(cnt_r, ptr_r, cur_r, cnt_s, ptr_s, cur_s);
  k_fill<<<EB,256,0,stream>>>(emeta, cur_r, cur_s, pr_pack, ps_pack);

  // ---- forward ----
  k_layer0_fwd<<<NB4,256,0,stream>>>(z_buf, ptr_r, pr_pack, Ft2_0, M0,
      Wout, theta, Wmix, Msc0, w_read0, Wup1, Wsc1,
      A00, h1, sc1, e_node);
  k_layer1_fwd_bwd<<<NB4,256,0,stream>>>(z_buf, ptr_r, pr_pack, Ft2_1, h1,
      Wout1, theta1, Wmix1, sc1, Wr1, Wr2,
      P1, Qtab, WoT1, w_read0, batch, e_node,
      gAr2, gF1, out_e);

  // ---- backward ----
  k_bwd_gH0<<<NB4,256,0,stream>>>(z_buf, ptr_s, ps_pack, Ft2_1, gAr2, WupT1, gF1,
      A00, WmixT0, WoT0, theta, gAr2);
  k_gr_force<<<EB4,256,0,stream>>>(emeta, evec, dF4, gAr2, h1, M0, out_f);
}

// Round 8
// 308.779 us; speedup vs baseline: 1.4166x; 1.3676x over previous
//
#include <hip/hip_runtime.h>
#include <math.h>

#define N_NODES 10000
#define N_EDGES 160000
#define G_SEG 16
#define ZDIM 10
#define KDIM 64
#define NBESS 8
#define HIDR 16
#define RMAXF 5.0f
#define AVG_NEI_F 16.0f
#define TBINS 256

__device__ __forceinline__ float siluf(float x){ float s = 1.0f/(1.0f+expf(-x)); return x*s; }
__device__ __forceinline__ float dsiluf(float x){ float s = 1.0f/(1.0f+expf(-x)); return s*(1.0f + x*(1.0f-s)); }

__device__ __forceinline__ float waveReduce(float v){
  for (int off = 32; off > 0; off >>= 1) v += __shfl_down(v, off);
  return v;
}

// decode from r (CSR slots hold r; padding holds -1)
__device__ __forceinline__ void r_decode(float r, int& b, float& fr, float& wm){
  wm = (r >= 0.f) ? 1.f : 0.f;
  float tp = fmaxf(r, 0.f) * (TBINS / RMAXF);
  b = (int)tp; if (b > TBINS-1) b = TBINS-1;
  fr = tp - (float)b;
}

// ---------------- merged setup ----------------
__global__ __launch_bounds__(256) void k_setup(
    const float* We, const float* Wup, const float* Wsc,
    const float* Wout, const float* Wmix,
    const float* Wr1,
    const float* attrs, const float* aE,
    float* M0, float* Msc0,
    float* WoT0, float* WoT1, float* WmixT0, float* WupT1,
    float* P1, float* Qtab,
    int* z_buf, float* e_node){
  int blk = blockIdx.x, tid = threadIdx.x;
  const float* Wmix1 = Wmix + KDIM*KDIM;
  const float* Wsc1  = Wsc + ZDIM*KDIM*KDIM;
  if (blk < 5){
    int idx = blk*256 + tid;
    if (idx < 1280){
      int which = idx >= 640;
      int t = which ? idx - 640 : idx;
      int z = t >> 6, j = t & 63;
      float acc = 0.f;
      if (!which){
        #pragma unroll 8
        for (int k = 0; k < KDIM; k++) acc += We[z*KDIM + k] * Wup[k*KDIM + j];
        M0[z*KDIM + j] = acc;
      } else {
        #pragma unroll 8
        for (int k = 0; k < KDIM; k++) acc += We[z*KDIM + k] * Wsc[(z*KDIM + k)*KDIM + j];
        Msc0[z*KDIM + j] = acc;
      }
    }
  } else if (blk < 69){
    int t = (blk-5)*256 + tid;   // 0..16383
    int arr = t >> 12;
    int rem = t & 4095;
    int j = rem >> 6, k = rem & 63;
    float v; float* dst;
    switch(arr){
      case 0: v = Wout[k*KDIM + j];                 dst = WoT0;   break;
      case 1: v = Wout[3*KDIM*KDIM + k*KDIM + j];   dst = WoT1;   break;
      case 2: v = Wmix[k*KDIM + j];                 dst = WmixT0; break;
      default:v = Wup[KDIM*KDIM + k*KDIM + j];      dst = WupT1;  break;
    }
    dst[rem] = v;
  } else if (blk < 73){
    int t = (blk-69)*256 + tid;  // 0..1023
    int h = t >> 6, k = t & 63;
    float acc = 0.f;
    #pragma unroll 8
    for (int j = 0; j < KDIM; j++) acc += Wr1[j*HIDR + h] * Wmix1[k*KDIM + j];
    P1[h*KDIM + k] = acc;
  } else if (blk < 113){
    int t = (blk-73)*256 + tid;  // 0..10239
    int z = t >> 10;
    int rem = t & 1023;
    int h = rem >> 6, k = rem & 63;
    float acc = 0.f;
    #pragma unroll 8
    for (int j = 0; j < KDIM; j++) acc += Wr1[j*HIDR + h] * Wsc1[(z*KDIM + k)*KDIM + j];
    Qtab[(z*HIDR + h)*KDIM + k] = acc;
  } else {
    int n = (blk-113)*256 + tid;
    if (n < N_NODES){
      int z = 0;
      for (int i = 1; i < ZDIM; i++) if (attrs[n*ZDIM+i] > 0.5f) z = i;
      z_buf[n] = z;
      e_node[n] = aE[z];
    }
  }
}

// edge geometry + packed edge meta + CSR degree counting (live edges only)
__global__ __launch_bounds__(256) void k_edge_setup(const float* pos, const float* shifts, const int* ei,
                                                    const int* z_buf,
                                                    float4* evec, int4* emeta,
                                                    int* cnt_r, int* cnt_s){
  int e = blockIdx.x*256 + threadIdx.x;
  int s = ei[e], rcv = ei[N_EDGES + e];
  float dx = pos[rcv*3+0] - pos[s*3+0] + shifts[e*3+0];
  float dy = pos[rcv*3+1] - pos[s*3+1] + shifts[e*3+1];
  float dz = pos[rcv*3+2] - pos[s*3+2] + shifts[e*3+2];
  float r = sqrtf(dx*dx + dy*dy + dz*dz + 1e-9f);
  evec[e] = make_float4(dx, dy, dz, r);
  emeta[e] = make_int4(__float_as_int(r), s, rcv, z_buf[s]);
  if (r < RMAXF){
    atomicAdd(&cnt_s[s], 1);
    atomicAdd(&cnt_r[rcv], 1);
  }
}

__global__ __launch_bounds__(1024) void k_scan(const int* cnt_r, int* ptr_r, int* cur_r,
                                               const int* cnt_s, int* ptr_s, int* cur_s){
  __shared__ int part[1024];
  int tid = threadIdx.x;
  const int* cnt = blockIdx.x ? cnt_s : cnt_r;
  int* ptr = blockIdx.x ? ptr_s : ptr_r;
  int* cur = blockIdx.x ? cur_s : cur_r;
  const int per = 10;
  int start = tid*per;
  int s = 0;
  for (int t = 0; t < per; t++){ int i = start + t; if (i < N_NODES) s += cnt[i]; }
  part[tid] = s; __syncthreads();
  for (int d = 1; d < 1024; d <<= 1){
    int v = (tid >= d) ? part[tid-d] : 0;
    __syncthreads();
    part[tid] += v;
    __syncthreads();
  }
  int run = part[tid] - s;
  for (int t = 0; t < per; t++){
    int i = start + t;
    if (i < N_NODES){ ptr[i] = run; cur[i] = run; run += cnt[i]; }
  }
  if (tid == 1023) ptr[N_NODES] = part[1023];
}

__global__ __launch_bounds__(256) void k_fill(const int4* emeta, int* cur_r, int* cur_s,
                                              int4* pr_pack, int4* ps_pack){
  int e = blockIdx.x*256 + threadIdx.x;
  int4 m = emeta[e];            // {r_bits, snd, rcv, ez}
  float r = __int_as_float(m.x);
  if (r >= RMAXF) return;
  int p = atomicAdd(&cur_s[m.y], 1);
  ps_pack[p] = make_int4(m.x, m.z, e, 0);          // {r, rcv, eid}
  int p2 = atomicAdd(&cur_r[m.z], 1);
  pr_pack[p2] = make_int4(m.x, m.y, m.w, e);       // {r, snd, ez, eid}
}

// ---------------- radial-MLP tables ----------------
__global__ __launch_bounds__(64) void k_table(const float* R1g, const float* R2g,
                                              const float* R3g, const float* R4g,
                                              float2* Ft2_0, float2* Ft2_1, float* dF4f){
  int t = blockIdx.x, j = threadIdx.x;
  __shared__ float efs[NBESS], defs[NBESS];
  __shared__ float xs[KDIM], dxs[KDIM];
  if (j < NBESS){
    double r = (double)t * (double)RMAXF / (double)TBINS;
    double w = (double)(j+1) * M_PI / (double)RMAXF;
    double c = sqrt(2.0 / (double)RMAXF);
    double bess, dbess;
    if (r < 1e-12){ bess = c*w; dbess = 0.0; }
    else {
      double sw = sin(w*r), cw = cos(w*r);
      bess = c*sw/r;
      dbess = c*(w*cw*r - sw)/(r*r);
    }
    double xx = r / (double)RMAXF;
    double f = 0.0, df = 0.0;
    if (xx < 1.0){
      double x2 = xx*xx, x4 = x2*x2, x5 = x4*xx, x6 = x5*xx, x7 = x6*xx;
      f = 1.0 - 21.0*x5 + 35.0*x6 - 15.0*x7;
      df = (-105.0*x4 + 210.0*x5 - 105.0*x6) / (double)RMAXF;
    }
    efs[j]  = (float)(bess*f);
    defs[j] = (float)(dbess*f + bess*df);
  }
  __syncthreads();
  for (int i = 0; i < 2; i++){
    const float* R1 = R1g + i*NBESS*KDIM;
    const float* R2 = R2g + i*KDIM*KDIM;
    const float* R3 = R3g + i*KDIM*KDIM;
    const float* R4 = R4g + i*KDIM*KDIM;
    float z = 0.f, dz = 0.f;
    for (int b = 0; b < NBESS; b++){ float w = R1[b*KDIM+j]; z += efs[b]*w; dz += defs[b]*w; }
    float v = siluf(z), dv = dsiluf(z)*dz;
    xs[j] = v; dxs[j] = dv; __syncthreads();
    z = 0.f; dz = 0.f;
    for (int k = 0; k < KDIM; k++){ float w = R2[k*KDIM+j]; z += xs[k]*w; dz += dxs[k]*w; }
    v = siluf(z); dv = dsiluf(z)*dz; __syncthreads();
    xs[j] = v; dxs[j] = dv; __syncthreads();
    z = 0.f; dz = 0.f;
    for (int k = 0; k < KDIM; k++){ float w = R3[k*KDIM+j]; z += xs[k]*w; dz += dxs[k]*w; }
    v = siluf(z); dv = dsiluf(z)*dz; __syncthreads();
    xs[j] = v; dxs[j] = dv; __syncthreads();
    z = 0.f; dz = 0.f;
    for (int k = 0; k < KDIM; k++){ float w = R4[k*KDIM+j]; z += xs[k]*w; dz += dxs[k]*w; }
    float2* Ft  = i ? Ft2_1 : Ft2_0;
    Ft[t*KDIM+j].x = z;  if (t > 0) Ft[(t-1)*KDIM+j].y = z;
    dF4f[(t*KDIM+j)*4 + 2*i] = dz;
    if (t > 0) dF4f[((t-1)*KDIM+j)*4 + 2*i + 1] = dz;
    __syncthreads();
  }
}

// ---------------- layer-0 forward (M0-table gather) + epilogue + h1/sc1 ----------------
__global__ __launch_bounds__(256) void k_layer0_fwd(
    const int* z_buf, const int* ptr_r, const int4* pr_pack,
    const float2* Ft2, const float* M0,
    const float* Wout0, const float* theta0, const float* Wmix0,
    const float* Msc0, const float* w_read0,
    const float* Wup1, const float* Wsc1,
    float* A0_out, float* h1, float* sc1, float* e_node){
  __shared__ float lds[4][KDIM];
  int tid = threadIdx.x;
  int w = tid >> 6, lane = tid & 63;
  int node = blockIdx.x*4 + w;
  int z = z_buf[node];
  int beg = ptr_r[node], end = ptr_r[node+1];
  int deg = end - beg;
  float acc0 = 0.f, acc1 = 0.f, acc2 = 0.f, acc3 = 0.f;
  for (int base = 0; base < deg; base += 64){
    int m = min(64, deg - base);
    float r_l = -1.f; int sz_l = 0;
    if (lane < m){
      int4 pk = pr_pack[beg + base + lane];   // {r, snd, ez, eid}
      r_l = __int_as_float(pk.x);
      sz_l = pk.z;
    }
    int i = 0;
    for (; i + 4 <= m; i += 4){
      float ra_ = __shfl(r_l, i),   rb_ = __shfl(r_l, i+1);
      float rc_ = __shfl(r_l, i+2), rd_ = __shfl(r_l, i+3);
      int za = __shfl(sz_l, i),   zb = __shfl(sz_l, i+1);
      int zc = __shfl(sz_l, i+2), zd = __shfl(sz_l, i+3);
      int ba, bb, bc, bd; float fa, fb, fc, fd, wa, wb, wc, wd;
      r_decode(ra_, ba, fa, wa); r_decode(rb_, bb, fb, wb);
      r_decode(rc_, bc, fc, wc); r_decode(rd_, bd, fd, wd);
      float2 Fa = Ft2[ba*KDIM + lane]; float ha = M0[za*KDIM + lane];
      float2 Fb = Ft2[bb*KDIM + lane]; float hb = M0[zb*KDIM + lane];
      float2 Fc = Ft2[bc*KDIM + lane]; float hc = M0[zc*KDIM + lane];
      float2 Fd = Ft2[bd*KDIM + lane]; float hd = M0[zd*KDIM + lane];
      acc0 += wa * (Fa.x + fa*(Fa.y - Fa.x)) * ha;
      acc1 += wb * (Fb.x + fb*(Fb.y - Fb.x)) * hb;
      acc2 += wc * (Fc.x + fc*(Fc.y - Fc.x)) * hc;
      acc3 += wd * (Fd.x + fd*(Fd.y - Fd.x)) * hd;
    }
    for (; i < m; i++){
      float ra_ = __shfl(r_l, i);
      int za = __shfl(sz_l, i);
      int ba; float fa, wa;
      r_decode(ra_, ba, fa, wa);
      float2 Fa = Ft2[ba*KDIM + lane]; float ha = M0[za*KDIM + lane];
      acc0 += wa * (Fa.x + fa*(Fa.y - Fa.x)) * ha;
    }
  }
  float acc = ((acc0 + acc1) + (acc2 + acc3)) * (1.0f/AVG_NEI_F);
  lds[w][lane] = acc;
  __syncthreads();
  float a0 = 0.f;
  #pragma unroll 4
  for (int k = 0; k < KDIM; k++) a0 += lds[w][k] * Wout0[k*KDIM + lane];
  A0_out[node*KDIM + lane] = a0;
  float t0 = theta0[(0*ZDIM + z)*KDIM + lane];
  float t1 = theta0[(1*ZDIM + z)*KDIM + lane];
  float t2 = theta0[(2*ZDIM + z)*KDIM + lane];
  float q = t0 + t1*a0 + t2*a0*a0;
  __syncthreads();
  lds[w][lane] = q*a0;
  __syncthreads();
  float f = 0.f;
  #pragma unroll 4
  for (int k = 0; k < KDIM; k++) f += lds[w][k] * Wmix0[k*KDIM + lane];
  f += Msc0[z*KDIM + lane];
  float p = f * w_read0[lane];
  p = waveReduce(p);
  if (lane == 0) e_node[node] += p;
  __syncthreads();
  lds[w][lane] = f;
  __syncthreads();
  float h = 0.f, s = 0.f;
  #pragma unroll 2
  for (int k = 0; k < KDIM; k++){
    float fv = lds[w][k];
    h += fv * Wup1[k*KDIM + lane];
    s += fv * Wsc1[(z*KDIM + k)*KDIM + lane];
  }
  h1[node*KDIM + lane] = h;
  sc1[node*KDIM + lane] = s;
}

// ---------------- layer-1 forward + node-local backward (P1/Q shortcut) ----------------
__global__ __launch_bounds__(256) void k_layer1_fwd_bwd(
    const int* z_buf, const int* ptr_r, const int4* pr_pack,
    const float2* Ft2, const float* h1,
    const float* Wout1, const float* theta1, const float* Wmix1,
    const float* sc1, const float* Wr1, const float* Wr2,
    const float* P1, const float* Qtab, const float* WoT1, const float* w_read0,
    float2* gAr2, float* gF1, float* e_node){
  __shared__ float lds[4][KDIM];
  int tid = threadIdx.x;
  int w = tid >> 6, lane = tid & 63;
  int node = blockIdx.x*4 + w;
  int beg = ptr_r[node], end = ptr_r[node+1];
  int deg = end - beg;
  float acc0 = 0.f, acc1 = 0.f, acc2 = 0.f, acc3 = 0.f;
  for (int base = 0; base < deg; base += 64){
    int m = min(64, deg - base);
    float r_l = -1.f; int snd_l = 0;
    if (lane < m){
      int4 pk = pr_pack[beg + base + lane];
      r_l = __int_as_float(pk.x);
      snd_l = pk.y;
    }
    int i = 0;
    for (; i + 4 <= m; i += 4){
      float ra_ = __shfl(r_l, i),   rb_ = __shfl(r_l, i+1);
      float rc_ = __shfl(r_l, i+2), rd_ = __shfl(r_l, i+3);
      int sa = __shfl(snd_l, i),   sb = __shfl(snd_l, i+1);
      int sc = __shfl(snd_l, i+2), sd = __shfl(snd_l, i+3);
      int ba, bb, bc, bd; float fa, fb, fc, fd, wa, wb, wc, wd;
      r_decode(ra_, ba, fa, wa); r_decode(rb_, bb, fb, wb);
      r_decode(rc_, bc, fc, wc); r_decode(rd_, bd, fd, wd);
      float2 Fa = Ft2[ba*KDIM + lane]; float ha = h1[sa*KDIM + lane];
      float2 Fb = Ft2[bb*KDIM + lane]; float hb = h1[sb*KDIM + lane];
      float2 Fc = Ft2[bc*KDIM + lane]; float hc = h1[sc*KDIM + lane];
      float2 Fd = Ft2[bd*KDIM + lane]; float hd = h1[sd*KDIM + lane];
      acc0 += wa * (Fa.x + fa*(Fa.y - Fa.x)) * ha;
      acc1 += wb * (Fb.x + fb*(Fb.y - Fb.x)) * hb;
      acc2 += wc * (Fc.x + fc*(Fc.y - Fc.x)) * hc;
      acc3 += wd * (Fd.x + fd*(Fd.y - Fd.x)) * hd;
    }
    for (; i < m; i++){
      float ra_ = __shfl(r_l, i);
      int sa = __shfl(snd_l, i);
      int ba; float fa, wa;
      r_decode(ra_, ba, fa, wa);
      float2 Fa = Ft2[ba*KDIM + lane]; float ha = h1[sa*KDIM + lane];
      acc0 += wa * (Fa.x + fa*(Fa.y - Fa.x)) * ha;
    }
  }
  float acc = ((acc0 + acc1) + (acc2 + acc3)) * (1.0f/AVG_NEI_F);
  int z = z_buf[node];
  lds[w][lane] = acc;
  __syncthreads();
  float a0 = 0.f;
  #pragma unroll 4
  for (int k = 0; k < KDIM; k++) a0 += lds[w][k] * Wout1[k*KDIM + lane];
  float t0 = theta1[(0*ZDIM + z)*KDIM + lane];
  float t1 = theta1[(1*ZDIM + z)*KDIM + lane];
  float t2 = theta1[(2*ZDIM + z)*KDIM + lane];
  float q = t0 + t1*a0 + t2*a0*a0;
  __syncthreads();
  lds[w][lane] = q*a0;
  __syncthreads();
  float f = 0.f;
  #pragma unroll 4
  for (int k = 0; k < KDIM; k++) f += lds[w][k] * Wmix1[k*KDIM + lane];
  f += sc1[node*KDIM + lane];
  __syncthreads();
  lds[w][lane] = f;
  __syncthreads();
  // readout: t = feats2 @ Wr1 (16 hidden)
  int hh = lane & 15;
  int quad = lane >> 4;
  float tpart = 0.f;
  #pragma unroll
  for (int jj = 0; jj < 16; jj++)
    tpart += lds[w][quad*16 + jj] * Wr1[(quad*16 + jj)*HIDR + hh];
  tpart += __shfl_xor(tpart, 16);
  tpart += __shfl_xor(tpart, 32);
  float ne = siluf(tpart) * Wr2[hh];
  ne = waveReduce(ne);
  if (lane == 0) e_node[node] += 0.25f * ne;   // private address: no contention
  // ---- backward (node-local), low-rank shortcut through readout ----
  float coeff = dsiluf(tpart) * Wr2[hh];   // replicated x4 across wave
  float gP = 0.f, gsc = 0.f;
  const float* Qz = Qtab + z*HIDR*KDIM;
  #pragma unroll
  for (int h2 = 0; h2 < HIDR; h2++){
    float cc = __shfl(coeff, h2);
    gP  += cc * P1[h2*KDIM + lane];
    gsc += cc * Qz[h2*KDIM + lane];
  }
  gF1[node*KDIM + lane] = w_read0[lane] + gsc;
  float u = t0 + 2.f*t1*a0 + 3.f*t2*a0*a0;
  __syncthreads();
  lds[w][lane] = gP * u;
  __syncthreads();
  float gAr = 0.f;
  #pragma unroll 4
  for (int j = 0; j < KDIM; j++) gAr += lds[w][j] * WoT1[j*KDIM + lane];
  gAr2[node*KDIM + lane].x = gAr * (1.0f/AVG_NEI_F);
}

// LDS pre-reduced energy: 40 blocks x 16 atomics = 640 atomics total
__global__ __launch_bounds__(256) void k_energy(const float* e_node, const int* batch, float* out_e){
  __shared__ float part[G_SEG];
  int tid = threadIdx.x;
  if (tid < G_SEG) part[tid] = 0.f;
  __syncthreads();
  int n = blockIdx.x*256 + tid;
  if (n < N_NODES) atomicAdd(&part[batch[n]], e_node[n]);
  __syncthreads();
  if (tid < G_SEG) atomicAdd(&out_e[tid], part[tid]);
}

// ---------------- bwd: sender-gather gH + layer-0 node bwd -> gAr0 ----------------
__global__ __launch_bounds__(256) void k_bwd_gH0(
    const int* z_buf, const int* ptr_s, const int4* ps_pack,
    const float2* Ft2_1, const float2* gAr2c, const float* WupT1, const float* gF1,
    const float* A00, const float* WmixT0, const float* WoT0, const float* theta0,
    float2* gAr2){
  __shared__ float ga[4][KDIM];
  __shared__ float gb[4][KDIM];
  int tid = threadIdx.x; int w = tid>>6, lane = tid&63;
  int node = blockIdx.x*4 + w;
  int beg = ptr_s[node], end = ptr_s[node+1];
  int deg = end - beg;
  float acc0 = 0.f, acc1 = 0.f, acc2 = 0.f, acc3 = 0.f;
  for (int base = 0; base < deg; base += 64){
    int m = min(64, deg - base);
    float r_l = -1.f; int rcv_l = 0;
    if (lane < m){
      int4 pk = ps_pack[beg + base + lane];   // {r, rcv, eid}
      r_l = __int_as_float(pk.x);
      rcv_l = pk.y;
    }
    int i = 0;
    for (; i + 4 <= m; i += 4){
      float ra_ = __shfl(r_l, i),   rb_ = __shfl(r_l, i+1);
      float rc_ = __shfl(r_l, i+2), rd_ = __shfl(r_l, i+3);
      int ra = __shfl(rcv_l, i),   rb = __shfl(rcv_l, i+1);
      int rc = __shfl(rcv_l, i+2), rd = __shfl(rcv_l, i+3);
      int ba, bb, bc, bd; float fa, fb, fc, fd, wa, wb, wc, wd;
      r_decode(ra_, ba, fa, wa); r_decode(rb_, bb, fb, wb);
      r_decode(rc_, bc, fc, wc); r_decode(rd_, bd, fd, wd);
      float2 Fa = Ft2_1[ba*KDIM + lane]; float ga_ = gAr2c[ra*KDIM + lane].x;
      float2 Fb = Ft2_1[bb*KDIM + lane]; float gb_ = gAr2c[rb*KDIM + lane].x;
      float2 Fc = Ft2_1[bc*KDIM + lane]; float gc_ = gAr2c[rc*KDIM + lane].x;
      float2 Fd = Ft2_1[bd*KDIM + lane]; float gd_ = gAr2c[rd*KDIM + lane].x;
      acc0 += wa * (Fa.x + fa*(Fa.y - Fa.x)) * ga_;
      acc1 += wb * (Fb.x + fb*(Fb.y - Fb.x)) * gb_;
      acc2 += wc * (Fc.x + fc*(Fc.y - Fc.x)) * gc_;
      acc3 += wd * (Fd.x + fd*(Fd.y - Fd.x)) * gd_;
    }
    for (; i < m; i++){
      float ra_ = __shfl(r_l, i);
      int ra = __shfl(rcv_l, i);
      int ba; float fa, wa;
      r_decode(ra_, ba, fa, wa);
      float2 Fa = Ft2_1[ba*KDIM + lane]; float ga_ = gAr2c[ra*KDIM + lane].x;
      acc0 += wa * (Fa.x + fa*(Fa.y - Fa.x)) * ga_;
    }
  }
  ga[w][lane] = ((acc0 + acc1) + (acc2 + acc3));
  __syncthreads();
  float gfh = 0.f;
  #pragma unroll 4
  for (int j = 0; j < KDIM; j++) gfh += ga[w][j] * WupT1[j*KDIM + lane];
  float gtot = gF1[node*KDIM + lane] + gfh;
  gb[w][lane] = gtot;
  __syncthreads();
  float gP = 0.f;
  #pragma unroll 4
  for (int j = 0; j < KDIM; j++) gP += gb[w][j] * WmixT0[j*KDIM + lane];
  int z = z_buf[node];
  float a = A00[node*KDIM + lane];
  float t0 = theta0[(0*ZDIM+z)*KDIM + lane];
  float t1 = theta0[(1*ZDIM+z)*KDIM + lane];
  float t2 = theta0[(2*ZDIM+z)*KDIM + lane];
  float u = t0 + 2.f*t1*a + 3.f*t2*a*a;
  __syncthreads();
  ga[w][lane] = gP * u;
  __syncthreads();
  float gAr = 0.f;
  #pragma unroll 4
  for (int j = 0; j < KDIM; j++) gAr += ga[w][j] * WoT0[j*KDIM + lane];
  gAr2[node*KDIM + lane].y = gAr * (1.0f/AVG_NEI_F);
}

// per-edge gr + fused force atomics (one wave per edge; dead edges exit early)
__global__ __launch_bounds__(256) void k_gr_force(const int4* emeta, const float4* evec,
                                                  const float4* dF4,
                                                  const float2* gAr2, const float* h1, const float* M0,
                                                  float* out_f){
  int tid = threadIdx.x;
  int w = tid>>6, lane = tid&63;
  int e = blockIdx.x*4 + w;
  int4 m = emeta[e];              // {r, snd, rcv, ez}
  float r = __int_as_float(m.x);
  if (r >= RMAXF) return;
  float tp = r * (TBINS / RMAXF);
  int b = (int)tp; if (b > TBINS-1) b = TBINS-1;
  float fr = tp - (float)b;
  float4 d4 = dF4[b*KDIM + lane];           // {d0.lo, d0.hi, d1.lo, d1.hi}
  float2 g  = gAr2[m.z*KDIM + lane];        // {g1, g0}
  float hv1 = h1[m.y*KDIM + lane];
  float hv0 = M0[m.w*KDIM + lane];
  float v = g.x*hv1*(d4.z + fr*(d4.w - d4.z)) + g.y*hv0*(d4.x + fr*(d4.y - d4.x));
  v = waveReduce(v);
  float s = __shfl(v, 0) / r;
  if (lane < 6){
    float4 ev = evec[e];
    int comp = lane < 3 ? lane : lane - 3;
    float cv = (comp == 0) ? ev.x : (comp == 1) ? ev.y : ev.z;
    float val = (lane < 3 ? s : -s) * cv;
    int nd = (lane < 3) ? m.y : m.z;
    atomicAdd(&out_f[nd*3 + comp], val);
  }
}

extern "C" void kernel_launch(void* const* d_in, const int* in_sizes, int n_in,
                              void* d_out, int out_size, void* d_ws, size_t ws_size,
                              hipStream_t stream){
  const float* pos    = (const float*)d_in[0];
  const float* attrs  = (const float*)d_in[1];
  const float* shifts = (const float*)d_in[2];
  const float* aE     = (const float*)d_in[3];
  const float* We     = (const float*)d_in[4];
  const float* Wup    = (const float*)d_in[5];
  const float* R1     = (const float*)d_in[6];
  const float* R2     = (const float*)d_in[7];
  const float* R3     = (const float*)d_in[8];
  const float* R4     = (const float*)d_in[9];
  const float* Wout   = (const float*)d_in[10];
  const float* Wsc    = (const float*)d_in[11];
  const float* theta  = (const float*)d_in[12];
  const float* Wmix   = (const float*)d_in[13];
  const float* w_read0= (const float*)d_in[14];
  const float* Wr1    = (const float*)d_in[15];
  const float* Wr2    = (const float*)d_in[16];
  const int*   ei     = (const int*)d_in[17];
  const int*   batch  = (const int*)d_in[18];

  char* base = (char*)d_ws;
  size_t off = 0;
  auto alloc = [&](size_t bytes)->void*{
    void* p = base + off;
    off = (off + bytes + 255) & ~(size_t)255;
    return p;
  };
  float4* evec   = (float4*)alloc(N_EDGES*sizeof(float4));
  int4*   emeta  = (int4*)alloc(N_EDGES*sizeof(int4));
  int4*   pr_pack= (int4*)alloc(N_EDGES*sizeof(int4));
  int4*   ps_pack= (int4*)alloc(N_EDGES*sizeof(int4));
  float*  e_node = (float*)alloc(N_NODES*sizeof(float));
  float*  h1     = (float*)alloc(N_NODES*KDIM*sizeof(float));
  float*  sc1    = (float*)alloc(N_NODES*KDIM*sizeof(float));
  float*  A00    = (float*)alloc(N_NODES*KDIM*sizeof(float));
  float*  gF1    = (float*)alloc(N_NODES*KDIM*sizeof(float));
  float2* gAr2   = (float2*)alloc(N_NODES*KDIM*sizeof(float2));
  float2* Ft2_0  = (float2*)alloc((TBINS+1)*KDIM*sizeof(float2));
  float2* Ft2_1  = (float2*)alloc((TBINS+1)*KDIM*sizeof(float2));
  float4* dF4    = (float4*)alloc((TBINS+1)*KDIM*sizeof(float4));
  float*  M0     = (float*)alloc(ZDIM*KDIM*sizeof(float));
  float*  Msc0   = (float*)alloc(ZDIM*KDIM*sizeof(float));
  float*  WoT0   = (float*)alloc(KDIM*KDIM*sizeof(float));
  float*  WoT1   = (float*)alloc(KDIM*KDIM*sizeof(float));
  float*  WmixT0 = (float*)alloc(KDIM*KDIM*sizeof(float));
  float*  WupT1  = (float*)alloc(KDIM*KDIM*sizeof(float));
  float*  P1     = (float*)alloc(HIDR*KDIM*sizeof(float));
  float*  Qtab   = (float*)alloc(ZDIM*HIDR*KDIM*sizeof(float));
  int* z_buf = (int*)alloc(N_NODES*sizeof(int));
  int* cnt_r = (int*)alloc(N_NODES*sizeof(int));
  int* cnt_s = (int*)alloc(N_NODES*sizeof(int));
  int* ptr_r = (int*)alloc((N_NODES+1)*sizeof(int));
  int* ptr_s = (int*)alloc((N_NODES+1)*sizeof(int));
  int* cur_r = (int*)alloc(N_NODES*sizeof(int));
  int* cur_s = (int*)alloc(N_NODES*sizeof(int));

  float* out_e = (float*)d_out;
  float* out_f = out_e + G_SEG;

  hipMemsetAsync(d_out, 0, (size_t)out_size*sizeof(float), stream);
  hipMemsetAsync(cnt_r, 0, N_NODES*sizeof(int), stream);
  hipMemsetAsync(cnt_s, 0, N_NODES*sizeof(int), stream);

  const int NB4 = N_NODES/4;
  const int EB  = N_EDGES/256;
  const int EB4 = N_EDGES/4;
  const int NBt = (N_NODES+255)/256;

  const float* Wup1 = Wup + KDIM*KDIM;
  const float* Wsc1 = Wsc + ZDIM*KDIM*KDIM;
  const float* Wout1 = Wout + 3*KDIM*KDIM;
  const float* theta1 = theta + 3*ZDIM*KDIM;
  const float* Wmix1 = Wmix + KDIM*KDIM;

  k_setup<<<153,256,0,stream>>>(We, Wup, Wsc, Wout, Wmix, Wr1, attrs, aE,
                                M0, Msc0, WoT0, WoT1, WmixT0, WupT1, P1, Qtab,
                                z_buf, e_node);
  k_table<<<TBINS+1,64,0,stream>>>(R1, R2, R3, R4, Ft2_0, Ft2_1, (float*)dF4);
  k_edge_setup<<<EB,256,0,stream>>>(pos, shifts, ei, z_buf, evec, emeta, cnt_r, cnt_s);
  k_scan<<<2,1024,0,stream>>>(cnt_r, ptr_r, cur_r, cnt_s, ptr_s, cur_s);
  k_fill<<<EB,256,0,stream>>>(emeta, cur_r, cur_s, pr_pack, ps_pack);

  // ---- forward ----
  k_layer0_fwd<<<NB4,256,0,stream>>>(z_buf, ptr_r, pr_pack, Ft2_0, M0,
      Wout, theta, Wmix, Msc0, w_read0, Wup1, Wsc1,
      A00, h1, sc1, e_node);
  k_layer1_fwd_bwd<<<NB4,256,0,stream>>>(z_buf, ptr_r, pr_pack, Ft2_1, h1,
      Wout1, theta1, Wmix1, sc1, Wr1, Wr2,
      P1, Qtab, WoT1, w_read0,
      gAr2, gF1, e_node);
  k_energy<<<NBt,256,0,stream>>>(e_node, batch, out_e);

  // ---- backward ----
  k_bwd_gH0<<<NB4,256,0,stream>>>(z_buf, ptr_s, ps_pack, Ft2_1, gAr2, WupT1, gF1,
      A00, WmixT0, WoT0, theta, gAr2);
  k_gr_force<<<EB4,256,0,stream>>>(emeta, evec, dF4, gAr2, h1, M0, out_f);
}